// Round 2
// baseline (2575.999 us; speedup 1.0000x reference)
//
#include <hip/hip_runtime.h>
#include <stdint.h>

#define NCH    64
#define HID    128
#define OUTC   64
#define NNODE  20000
#define NEDGE  640000
#define FDIM   133
#define PHIN   193
#define TE     32
#define EST    36
#define TN     32
#define NST    36
#define LN_EPS 1e-5f

__device__ __forceinline__ float sp(float xv) {
    // softplus = max(x,0) + log1p(exp(-|x|))
    return fmaxf(xv, 0.f) + log1pf(expf(-fabsf(xv)));
}
__device__ __forceinline__ void atomAddF(float* p, float v) {
    __hip_atomic_fetch_add(p, v, __ATOMIC_RELAXED, __HIP_MEMORY_SCOPE_AGENT);
}

// ---------------------------------------------------------------- edge kernel
__global__ __launch_bounds__(256)
void eg_edge(const float* __restrict__ x, const float* __restrict__ pos,
             const float* __restrict__ vel,
             const float* __restrict__ We1, const float* __restrict__ be1,
             const float* __restrict__ ge1, const float* __restrict__ bte1,
             const float* __restrict__ We2, const float* __restrict__ be2,
             const float* __restrict__ We3, const float* __restrict__ be3,
             const float* __restrict__ Wv1, const float* __restrict__ bv1,
             const float* __restrict__ gv1, const float* __restrict__ btv1,
             const float* __restrict__ Wv2, const float* __restrict__ bv2,
             const int* __restrict__ ei,
             float* __restrict__ mh, float* __restrict__ mv,
             float* __restrict__ cnt)
{
    __shared__ float tmp_s[FDIM * EST];   // 19152 B  input features [k][e]
    __shared__ float A_s[HID * EST];      // 18432 B  h1 path
    __shared__ float B_s[HID * EST];      // 18432 B  v1 / h2 path
    __shared__ int   dst_s[TE], src_s[TE];
    __shared__ float rel_s[TE * 2];
    __shared__ float vw_s[TE];
    __shared__ float mu_s[64], rs_s[64];

    const int tid = threadIdx.x;
    const int e_base = blockIdx.x * TE;

    // ---- phase 0: indices + geometric features
    if (tid < TE) {
        int gi = e_base + tid;
        int s = ei[gi];
        int d = ei[NEDGE + gi];
        src_s[tid] = s; dst_s[tid] = d;
        float rx = pos[2 * s]     - pos[2 * d];
        float ry = pos[2 * s + 1] - pos[2 * d + 1];
        float vx = vel[2 * s]     - vel[2 * d];
        float vy = vel[2 * s + 1] - vel[2 * d + 1];
        float dsq = rx * rx + ry * ry;
        float dvr = vx * rx + vy * ry;
        float r2  = fminf(1.0f / (dsq + 0.05f), 20.0f);
        float r6  = fminf(r2 * r2 * r2, 400.0f);
        float r12 = fminf(r6 * r6, 160000.0f);
        tmp_s[128 * EST + tid] = dsq;
        tmp_s[129 * EST + tid] = dvr;
        tmp_s[130 * EST + tid] = r2;
        tmp_s[131 * EST + tid] = r6;
        tmp_s[132 * EST + tid] = r12;
        rel_s[2 * tid] = rx; rel_s[2 * tid + 1] = ry;
    }
    __syncthreads();

    // ---- phase 1: gather x[dst], x[src] into tmp rows 0..127
    {
        const int c = tid & 63, eg = tid >> 6;
        #pragma unroll
        for (int it = 0; it < 8; ++it) {
            int e = it * 4 + eg;
            int d = dst_s[e], s = src_s[e];
            tmp_s[c * EST + e]         = x[(size_t)d * NCH + c];
            tmp_s[(NCH + c) * EST + e] = x[(size_t)s * NCH + c];
        }
    }
    __syncthreads();

    const int e0 = (tid & 7) * 4;
    const int j0 = (tid >> 3) * 4;

    // ---- phase 2: dual GEMM1 (We1 & Wv1 share A reads), K=133
    {
        float ae[4][4] = {}; float av[4][4] = {};
        for (int k = 0; k < FDIM; ++k) {
            const float4 a  = *(const float4*)&tmp_s[k * EST + e0];
            const float4 we = *(const float4*)(We1 + (size_t)k * HID + j0);
            const float4 wv = *(const float4*)(Wv1 + (size_t)k * HID + j0);
            const float wE[4] = { we.x, we.y, we.z, we.w };
            const float wV[4] = { wv.x, wv.y, wv.z, wv.w };
            const float aa[4] = { a.x, a.y, a.z, a.w };
            #pragma unroll
            for (int i = 0; i < 4; ++i)
                #pragma unroll
                for (int j = 0; j < 4; ++j) {
                    ae[i][j] += aa[i] * wE[j];
                    av[i][j] += aa[i] * wV[j];
                }
        }
        #pragma unroll
        for (int j = 0; j < 4; ++j) {
            float be = be1[j0 + j], bv = bv1[j0 + j];
            #pragma unroll
            for (int i = 0; i < 4; ++i) {
                A_s[(j0 + j) * EST + e0 + i] = ae[i][j] + be;
                B_s[(j0 + j) * EST + e0 + i] = av[i][j] + bv;
            }
        }
    }
    __syncthreads();

    // ---- phase 3: LN stats for both buffers
    if (tid < 64) {
        const int e = tid & 31;
        const float* buf = (tid < 32) ? A_s : B_s;
        float sum = 0.f, sq = 0.f;
        for (int k = 0; k < HID; ++k) {
            float v = buf[k * EST + e];
            sum += v; sq += v * v;
        }
        float mu = sum * (1.0f / HID);
        float var = sq * (1.0f / HID) - mu * mu;
        mu_s[tid] = mu;
        rs_s[tid] = rsqrtf(var + LN_EPS);
    }
    __syncthreads();

    // ---- phase 4: normalize + softplus (both buffers)
    {
        const int e = tid & 31;
        const int bsel = (tid >> 5) & 1;
        const int jb = (tid >> 6) * 32;
        float* P = bsel ? B_s : A_s;
        const float* g  = bsel ? gv1 : ge1;
        const float* bt = bsel ? btv1 : bte1;
        const float mu = mu_s[bsel * 32 + e];
        const float rs = rs_s[bsel * 32 + e];
        for (int jj = 0; jj < 32; ++jj) {
            int j = jb + jj;
            float v = P[j * EST + e];
            v = (v - mu) * rs * g[j] + bt[j];
            P[j * EST + e] = sp(v);
        }
    }
    __syncthreads();

    // ---- phase 5: v_w = v1 . Wv2 + bv2
    if (tid < TE) {
        float s = 0.f;
        for (int k = 0; k < HID; ++k) s += B_s[k * EST + tid] * Wv2[k];
        vw_s[tid] = s + bv2[0];
    }
    __syncthreads();

    // ---- phase 6: GEMM2 h2 = softplus(h1 @ We2 + be2) -> B_s
    {
        float acc[4][4] = {};
        for (int k = 0; k < HID; ++k) {
            const float4 a = *(const float4*)&A_s[k * EST + e0];
            const float4 wb = *(const float4*)(We2 + (size_t)k * HID + j0);
            const float w[4] = { wb.x, wb.y, wb.z, wb.w };
            const float aa[4] = { a.x, a.y, a.z, a.w };
            #pragma unroll
            for (int i = 0; i < 4; ++i)
                #pragma unroll
                for (int j = 0; j < 4; ++j) acc[i][j] += aa[i] * w[j];
        }
        #pragma unroll
        for (int j = 0; j < 4; ++j) {
            float be = be2[j0 + j];
            #pragma unroll
            for (int i = 0; i < 4; ++i)
                B_s[(j0 + j) * EST + e0 + i] = sp(acc[i][j] + be);
        }
    }
    __syncthreads();

    // ---- phase 7: GEMM3 m_h_e = h2 @ We3 + be3, atomic scatter-add
    {
        float acc[4][4] = {};
        for (int k = 0; k < HID; ++k) {
            const float4 a = *(const float4*)&B_s[k * EST + e0];
            const float4 wb = *(const float4*)(We3 + (size_t)k * HID + j0);
            const float w[4] = { wb.x, wb.y, wb.z, wb.w };
            const float aa[4] = { a.x, a.y, a.z, a.w };
            #pragma unroll
            for (int i = 0; i < 4; ++i)
                #pragma unroll
                for (int j = 0; j < 4; ++j) acc[i][j] += aa[i] * w[j];
        }
        #pragma unroll
        for (int j = 0; j < 4; ++j) {
            float b3 = be3[j0 + j];
            #pragma unroll
            for (int i = 0; i < 4; ++i)
                atomAddF(&mh[(size_t)dst_s[e0 + i] * HID + j0 + j], acc[i][j] + b3);
        }
    }
    // ---- phase 8: m_v and count atomics
    if (tid < TE) {
        int d = dst_s[tid];
        float w = vw_s[tid];
        atomAddF(&mv[2 * d],     w * rel_s[2 * tid]);
        atomAddF(&mv[2 * d + 1], w * rel_s[2 * tid + 1]);
        atomAddF(&cnt[d], 1.0f);
    }
}

// ---------------------------------------------------------------- node kernel
__global__ __launch_bounds__(256)
void eg_node(const float* __restrict__ x,
             const float* __restrict__ Wh1, const float* __restrict__ bh1,
             const float* __restrict__ gh1, const float* __restrict__ bth1,
             const float* __restrict__ Wh2, const float* __restrict__ bh2,
             const float* __restrict__ mh, const float* __restrict__ mv,
             const float* __restrict__ cnt, float* __restrict__ out)
{
    __shared__ float hin_s[PHIN * NST];   // 27792 B
    __shared__ float H_s[HID * NST];      // 18432 B
    __shared__ float den_s[TN], mu_s[TN], rs_s[TN];

    const int tid = threadIdx.x;
    const int n_base = blockIdx.x * TN;

    if (tid < TN) {
        int n = n_base + tid;
        float den = 1.f, norm = 0.f;
        if (n < NNODE) {
            den = fmaxf(cnt[n], 1.0f);
            float ax = mv[2 * n] / den + 1e-8f;
            float ay = mv[2 * n + 1] / den + 1e-8f;
            norm = sqrtf(ax * ax + ay * ay);
        }
        den_s[tid] = den;
        hin_s[192 * NST + tid] = norm;
    }
    __syncthreads();
    {
        const int c = tid & 63, ng = tid >> 6;
        #pragma unroll
        for (int it = 0; it < 8; ++it) {
            int nl = it * 4 + ng;
            int n = n_base + nl;
            hin_s[c * NST + nl] = (n < NNODE) ? x[(size_t)n * NCH + c] : 0.f;
        }
        const int k = tid & 127, ng2 = tid >> 7;
        #pragma unroll
        for (int it = 0; it < 16; ++it) {
            int nl = it * 2 + ng2;
            int n = n_base + nl;
            hin_s[(NCH + k) * NST + nl] =
                (n < NNODE) ? mh[(size_t)n * HID + k] / den_s[nl] : 0.f;
        }
    }
    __syncthreads();

    const int n0 = (tid & 7) * 4;
    const int j0 = (tid >> 3) * 4;

    // GEMM: hin @ Wh1 + bh1, K=193
    {
        float acc[4][4] = {};
        for (int k = 0; k < PHIN; ++k) {
            const float4 a = *(const float4*)&hin_s[k * NST + n0];
            const float4 wb = *(const float4*)(Wh1 + (size_t)k * HID + j0);
            const float w[4] = { wb.x, wb.y, wb.z, wb.w };
            const float aa[4] = { a.x, a.y, a.z, a.w };
            #pragma unroll
            for (int i = 0; i < 4; ++i)
                #pragma unroll
                for (int j = 0; j < 4; ++j) acc[i][j] += aa[i] * w[j];
        }
        #pragma unroll
        for (int j = 0; j < 4; ++j) {
            float b = bh1[j0 + j];
            #pragma unroll
            for (int i = 0; i < 4; ++i)
                H_s[(j0 + j) * NST + n0 + i] = acc[i][j] + b;
        }
    }
    __syncthreads();

    if (tid < TN) {
        float sum = 0.f, sq = 0.f;
        for (int k = 0; k < HID; ++k) {
            float v = H_s[k * NST + tid];
            sum += v; sq += v * v;
        }
        float mu = sum * (1.0f / HID);
        float var = sq * (1.0f / HID) - mu * mu;
        mu_s[tid] = mu;
        rs_s[tid] = rsqrtf(var + LN_EPS);
    }
    __syncthreads();
    {
        const int nl = tid & 31;
        const int jb = (tid >> 5) * 16;
        const float mu = mu_s[nl], rs = rs_s[nl];
        for (int jj = 0; jj < 16; ++jj) {
            int j = jb + jj;
            float v = H_s[j * NST + nl];
            v = (v - mu) * rs * gh1[j] + bth1[j];
            H_s[j * NST + nl] = sp(v);
        }
    }
    __syncthreads();

    // GEMM out: hu @ Wh2 + bh2 + x   (Wh2 rows are 64 wide)
    {
        const int o0 = (tid >> 3) * 2;
        float acc[4][2] = {};
        for (int k = 0; k < HID; ++k) {
            const float4 a = *(const float4*)&H_s[k * NST + n0];
            const float2 wb = *(const float2*)(Wh2 + (size_t)k * OUTC + o0);
            const float aa[4] = { a.x, a.y, a.z, a.w };
            #pragma unroll
            for (int i = 0; i < 4; ++i) {
                acc[i][0] += aa[i] * wb.x;
                acc[i][1] += aa[i] * wb.y;
            }
        }
        #pragma unroll
        for (int jo = 0; jo < 2; ++jo) {
            float bo = bh2[o0 + jo];
            #pragma unroll
            for (int i = 0; i < 4; ++i) {
                int n = n_base + n0 + i;
                if (n < NNODE) {
                    out[(size_t)n * OUTC + o0 + jo] =
                        x[(size_t)n * NCH + o0 + jo] + acc[i][jo] + bo;
                }
            }
        }
    }
}

// ---------------------------------------------------------------- launch
extern "C" void kernel_launch(void* const* d_in, const int* in_sizes, int n_in,
                              void* d_out, int out_size, void* d_ws, size_t ws_size,
                              hipStream_t stream)
{
    const float* x    = (const float*)d_in[0];
    const float* pos  = (const float*)d_in[1];
    const float* vel  = (const float*)d_in[2];
    const float* We1  = (const float*)d_in[3];
    const float* be1  = (const float*)d_in[4];
    const float* ge1  = (const float*)d_in[5];
    const float* bte1 = (const float*)d_in[6];
    const float* We2  = (const float*)d_in[7];
    const float* be2  = (const float*)d_in[8];
    const float* We3  = (const float*)d_in[9];
    const float* be3  = (const float*)d_in[10];
    const float* Wv1  = (const float*)d_in[11];
    const float* bv1  = (const float*)d_in[12];
    const float* gv1  = (const float*)d_in[13];
    const float* btv1 = (const float*)d_in[14];
    const float* Wv2  = (const float*)d_in[15];
    const float* bv2  = (const float*)d_in[16];
    const float* Wh1  = (const float*)d_in[17];
    const float* bh1  = (const float*)d_in[18];
    const float* gh1  = (const float*)d_in[19];
    const float* bth1 = (const float*)d_in[20];
    const float* Wh2  = (const float*)d_in[21];
    const float* bh2  = (const float*)d_in[22];
    const int*   ei   = (const int*)d_in[23];

    float* mh  = (float*)d_ws;                       // [N,128]
    float* mv  = mh + (size_t)NNODE * HID;           // [N,2]
    float* cnt = mv + (size_t)NNODE * 2;             // [N]
    size_t zbytes = ((size_t)NNODE * HID + (size_t)NNODE * 2 + NNODE) * sizeof(float);
    hipMemsetAsync(d_ws, 0, zbytes, stream);

    eg_edge<<<dim3(NEDGE / TE), dim3(256), 0, stream>>>(
        x, pos, vel, We1, be1, ge1, bte1, We2, be2, We3, be3,
        Wv1, bv1, gv1, btv1, Wv2, bv2, ei, mh, mv, cnt);

    eg_node<<<dim3((NNODE + TN - 1) / TN), dim3(256), 0, stream>>>(
        x, Wh1, bh1, gh1, bth1, Wh2, bh2, mh, mv, cnt, (float*)d_out);
}

// Round 3
// 980.615 us; speedup vs baseline: 2.6269x; 2.6269x over previous
//
#include <hip/hip_runtime.h>
#include <stdint.h>

#define NCH    64
#define HID    128
#define OUTC   64
#define NNODE  20000
#define NEDGE  640000
#define FDIM   133
#define PHIN   193
#define TE     32
#define TN     32
#define NST    36
#define LN_EPS 1e-5f
#define KP1    160          // K of GEMM1, padded (133 -> 160 = 5*32)
#define KP2    128          // K of GEMM2/3
#define CSTR   132          // fp32 C buffer row stride (dwords)

typedef __attribute__((ext_vector_type(8))) short bf16x8;
typedef __attribute__((ext_vector_type(4))) float f32x4;

__device__ __forceinline__ unsigned short f2bf(float f) {
    union { float f; unsigned int i; } v; v.f = f;
    unsigned int b = v.i;
    return (unsigned short)((b + 0x7FFFu + ((b >> 16) & 1u)) >> 16);
}
__device__ __forceinline__ float sp(float xv) {
    return fmaxf(xv, 0.f) + log1pf(expf(-fabsf(xv)));
}
__device__ __forceinline__ void atomAddF(float* p, float v) {
    __hip_atomic_fetch_add(p, v, __ATOMIC_RELAXED, __HIP_MEMORY_SCOPE_AGENT);
}
// A/B fragment offset in a [kstep][mtile(2)][lane(64)][8] bf16 buffer
__device__ __forceinline__ int fragOff(int ks, int mt, int lanepos) {
    return ((ks * 2 + mt) * 64 + lanepos) * 8;
}

// Workspace layout (floats): mh[20000*128] mv[20000*2] cnt[20000], then bf16 WT
#define WS_WFLOAT (NNODE * HID + NNODE * 2 + NNODE)   // 2,620,000 floats
#define WT_WE1 0
#define WT_WV1 (128 * KP1)
#define WT_WE2 (2 * 128 * KP1)
#define WT_WE3 (2 * 128 * KP1 + 128 * KP2)
#define WT_TOTAL (2 * 128 * KP1 + 2 * 128 * KP2)      // 73728 shorts

// ------------------------------------------------- weight transpose/convert
__global__ __launch_bounds__(256)
void eg_prep(const float* __restrict__ We1, const float* __restrict__ Wv1,
             const float* __restrict__ We2, const float* __restrict__ We3,
             short* __restrict__ wt)
{
    int idx = blockIdx.x * 256 + threadIdx.x;
    if (idx >= WT_TOTAL) return;
    if (idx < WT_WV1) {
        int n = idx / KP1, k = idx % KP1;
        wt[idx] = (k < FDIM) ? (short)f2bf(We1[(size_t)k * HID + n]) : (short)0;
    } else if (idx < WT_WE2) {
        int r = idx - WT_WV1; int n = r / KP1, k = r % KP1;
        wt[idx] = (k < FDIM) ? (short)f2bf(Wv1[(size_t)k * HID + n]) : (short)0;
    } else if (idx < WT_WE3) {
        int r = idx - WT_WE2; int n = r / KP2, k = r % KP2;
        wt[idx] = (short)f2bf(We2[(size_t)k * HID + n]);
    } else {
        int r = idx - WT_WE3; int n = r / KP2, k = r % KP2;
        wt[idx] = (short)f2bf(We3[(size_t)k * HID + n]);
    }
}

// ---------------------------------------------------------------- edge kernel
__global__ __launch_bounds__(256)
void eg_edge(const float* __restrict__ x, const float* __restrict__ pos,
             const float* __restrict__ vel,
             const float* __restrict__ be1, const float* __restrict__ ge1,
             const float* __restrict__ bte1, const float* __restrict__ be2,
             const float* __restrict__ be3,
             const float* __restrict__ bv1, const float* __restrict__ gv1,
             const float* __restrict__ btv1,
             const float* __restrict__ Wv2, const float* __restrict__ bv2,
             const short* __restrict__ wt,
             const int* __restrict__ ei,
             float* __restrict__ mh, float* __restrict__ mv,
             float* __restrict__ cnt)
{
    __shared__ __align__(16) short frag_s[5 * 2 * 64 * 8];   // 10240 B, A1 then A2 then A3
    __shared__ __align__(16) float C_s[2 * TE * CSTR];        // 33792 B
    __shared__ float psum_s[512], psq_s[512];                 // 4096 B
    __shared__ float mu_s[64], rs_s[64];
    __shared__ int   dst_s[TE], src_s[TE];
    __shared__ float rel_s[TE * 2], vw_s[TE];

    const int tid  = threadIdx.x;
    const int lane = tid & 63;
    const int wid  = tid >> 6;
    const int lr   = lane & 15;
    const int quad = lane >> 4;
    const int n0w  = wid * 32;
    const int e_base = blockIdx.x * TE;

    const short* We1T = wt + WT_WE1;
    const short* Wv1T = wt + WT_WV1;
    const short* We2T = wt + WT_WE2;
    const short* We3T = wt + WT_WE3;

    // ---- P0: indices + geometry (regs), zero kstep-4 frag region
    float geo[5]; int eS = -1, eD = -1;
    if (tid < TE) {
        int gi = e_base + tid;
        eS = ei[gi];
        eD = ei[NEDGE + gi];
        src_s[tid] = eS; dst_s[tid] = eD;
        float rx = pos[2 * eS]     - pos[2 * eD];
        float ry = pos[2 * eS + 1] - pos[2 * eD + 1];
        float vx = vel[2 * eS]     - vel[2 * eD];
        float vy = vel[2 * eS + 1] - vel[2 * eD + 1];
        float dsq = rx * rx + ry * ry;
        float dvr = vx * rx + vy * ry;
        float r2  = fminf(1.0f / (dsq + 0.05f), 20.0f);
        float r6  = fminf(r2 * r2 * r2, 400.0f);
        float r12 = fminf(r6 * r6, 160000.0f);
        geo[0] = dsq; geo[1] = dvr; geo[2] = r2; geo[3] = r6; geo[4] = r12;
        rel_s[2 * tid] = rx; rel_s[2 * tid + 1] = ry;
    }
    if (tid < 128) {   // zero kstep 4 region (2*64*8 shorts = 2048 B)
        int4 z = {0, 0, 0, 0};
        *(int4*)&frag_s[4 * 2 * 64 * 8 + tid * 8] = z;
    }
    __syncthreads();

    // ---- P1: geo shorts + gather x into A1 fragments (bf16)
    if (tid < TE) {
        int off = fragOff(4, tid >> 4, (tid & 15));   // kq=0, m=tid&15
        #pragma unroll
        for (int j = 0; j < 5; ++j) frag_s[off + j] = (short)f2bf(geo[j]);
    }
    {
        const int e = tid & 31, slot = tid >> 5;
        const int d = dst_s[e], s = src_s[e];
        #pragma unroll
        for (int h = 0; h < 2; ++h) {
            int o = slot + h * 8;              // octet 0..15, k0 = o*8
            int node = h ? s : d;
            int c0 = (o & 7) * 8;
            const float4 a0 = *(const float4*)&x[(size_t)node * NCH + c0];
            const float4 a1 = *(const float4*)&x[(size_t)node * NCH + c0 + 4];
            bf16x8 v;
            v[0] = (short)f2bf(a0.x); v[1] = (short)f2bf(a0.y);
            v[2] = (short)f2bf(a0.z); v[3] = (short)f2bf(a0.w);
            v[4] = (short)f2bf(a1.x); v[5] = (short)f2bf(a1.y);
            v[6] = (short)f2bf(a1.z); v[7] = (short)f2bf(a1.w);
            int ks = o >> 2, kq = o & 3;
            *(bf16x8*)&frag_s[fragOff(ks, e >> 4, kq * 16 + (e & 15))] = v;
        }
    }
    __syncthreads();

    // ---- P2: dual GEMM1 via MFMA (M=32, N=128, K=160)
    f32x4 zero4 = {0.f, 0.f, 0.f, 0.f};
    {
        f32x4 accE[2][2], accV[2][2];
        #pragma unroll
        for (int mt = 0; mt < 2; ++mt)
            #pragma unroll
            for (int nt = 0; nt < 2; ++nt) { accE[mt][nt] = zero4; accV[mt][nt] = zero4; }
        for (int ks = 0; ks < 5; ++ks) {
            bf16x8 af0 = *(const bf16x8*)&frag_s[fragOff(ks, 0, lane)];
            bf16x8 af1 = *(const bf16x8*)&frag_s[fragOff(ks, 1, lane)];
            int krow = ks * 32 + quad * 8;
            #pragma unroll
            for (int nt = 0; nt < 2; ++nt) {
                int n = n0w + nt * 16 + lr;
                bf16x8 bwE = *(const bf16x8*)&We1T[n * KP1 + krow];
                bf16x8 bwV = *(const bf16x8*)&Wv1T[n * KP1 + krow];
                accE[0][nt] = __builtin_amdgcn_mfma_f32_16x16x32_bf16(af0, bwE, accE[0][nt], 0, 0, 0);
                accE[1][nt] = __builtin_amdgcn_mfma_f32_16x16x32_bf16(af1, bwE, accE[1][nt], 0, 0, 0);
                accV[0][nt] = __builtin_amdgcn_mfma_f32_16x16x32_bf16(af0, bwV, accV[0][nt], 0, 0, 0);
                accV[1][nt] = __builtin_amdgcn_mfma_f32_16x16x32_bf16(af1, bwV, accV[1][nt], 0, 0, 0);
            }
        }
        // C write + bias (C layout: row = quad*4+r, col = lr)
        #pragma unroll
        for (int nt = 0; nt < 2; ++nt) {
            int n = n0w + nt * 16 + lr;
            float be = be1[n], bv = bv1[n];
            #pragma unroll
            for (int mt = 0; mt < 2; ++mt)
                #pragma unroll
                for (int r = 0; r < 4; ++r) {
                    int row = mt * 16 + quad * 4 + r;
                    C_s[row * CSTR + n]            = accE[mt][nt][r] + be;
                    C_s[TE * CSTR + row * CSTR + n] = accV[mt][nt][r] + bv;
                }
        }
    }
    __syncthreads();

    // ---- P3: LN partial stats (both paths), 256 threads
    {
        const int e = tid & 31, seg = tid >> 5;
        float s0 = 0.f, q0 = 0.f, s1 = 0.f, q1 = 0.f;
        #pragma unroll
        for (int j = seg * 16; j < seg * 16 + 16; ++j) {
            float v0 = C_s[e * CSTR + j];
            float v1 = C_s[TE * CSTR + e * CSTR + j];
            s0 += v0; q0 += v0 * v0;
            s1 += v1; q1 += v1 * v1;
        }
        psum_s[e * 8 + seg] = s0;       psq_s[e * 8 + seg] = q0;
        psum_s[256 + e * 8 + seg] = s1; psq_s[256 + e * 8 + seg] = q1;
    }
    __syncthreads();
    if (tid < 64) {
        int p = tid >> 5, e = tid & 31;
        float s = 0.f, q = 0.f;
        #pragma unroll
        for (int g = 0; g < 8; ++g) { s += psum_s[p * 256 + e * 8 + g]; q += psq_s[p * 256 + e * 8 + g]; }
        float mu = s * (1.0f / HID);
        float var = q * (1.0f / HID) - mu * mu;
        mu_s[p * 32 + e] = mu;
        rs_s[p * 32 + e] = rsqrtf(var + LN_EPS);
    }
    __syncthreads();

    // ---- P4a: h-path LN+softplus -> bf16 A2 fragments
    #pragma unroll
    for (int it = 0; it < 2; ++it) {
        int item = tid + it * 256;         // 0..511
        int e = item & 31, o = item >> 5;  // octet 0..15
        float mu = mu_s[e], rs = rs_s[e];
        const float4 v0 = *(const float4*)&C_s[e * CSTR + o * 8];
        const float4 v1 = *(const float4*)&C_s[e * CSTR + o * 8 + 4];
        const float4 g0 = *(const float4*)&ge1[o * 8];
        const float4 g1 = *(const float4*)&ge1[o * 8 + 4];
        const float4 t0 = *(const float4*)&bte1[o * 8];
        const float4 t1 = *(const float4*)&bte1[o * 8 + 4];
        float vv[8] = { v0.x, v0.y, v0.z, v0.w, v1.x, v1.y, v1.z, v1.w };
        float gg[8] = { g0.x, g0.y, g0.z, g0.w, g1.x, g1.y, g1.z, g1.w };
        float tt[8] = { t0.x, t0.y, t0.z, t0.w, t1.x, t1.y, t1.z, t1.w };
        bf16x8 outv;
        #pragma unroll
        for (int j = 0; j < 8; ++j)
            outv[j] = (short)f2bf(sp((vv[j] - mu) * rs * gg[j] + tt[j]));
        *(bf16x8*)&frag_s[fragOff(o >> 2, e >> 4, (o & 3) * 16 + (e & 15))] = outv;
    }
    // ---- P4b: v-path LN+softplus+dot(Wv2) partials
    {
        const int e = tid & 31, seg = tid >> 5;
        float mu = mu_s[32 + e], rs = rs_s[32 + e];
        float acc = 0.f;
        #pragma unroll
        for (int j = seg * 16; j < seg * 16 + 16; ++j) {
            float v = C_s[TE * CSTR + e * CSTR + j];
            v = (v - mu) * rs * gv1[j] + btv1[j];
            acc += sp(v) * Wv2[j];
        }
        psum_s[seg * 32 + e] = acc;
    }
    __syncthreads();
    if (tid < TE) {
        float s = 0.f;
        #pragma unroll
        for (int g = 0; g < 8; ++g) s += psum_s[g * 32 + tid];
        vw_s[tid] = s + bv2[0];
    }

    // ---- P5: GEMM2 (M=32, N=128, K=128) + softplus -> A3 fragments
    {
        f32x4 acc2[2][2];
        #pragma unroll
        for (int mt = 0; mt < 2; ++mt)
            #pragma unroll
            for (int nt = 0; nt < 2; ++nt) acc2[mt][nt] = zero4;
        for (int ks = 0; ks < 4; ++ks) {
            bf16x8 af0 = *(const bf16x8*)&frag_s[fragOff(ks, 0, lane)];
            bf16x8 af1 = *(const bf16x8*)&frag_s[fragOff(ks, 1, lane)];
            int krow = ks * 32 + quad * 8;
            #pragma unroll
            for (int nt = 0; nt < 2; ++nt) {
                int n = n0w + nt * 16 + lr;
                bf16x8 bw = *(const bf16x8*)&We2T[n * KP2 + krow];
                acc2[0][nt] = __builtin_amdgcn_mfma_f32_16x16x32_bf16(af0, bw, acc2[0][nt], 0, 0, 0);
                acc2[1][nt] = __builtin_amdgcn_mfma_f32_16x16x32_bf16(af1, bw, acc2[1][nt], 0, 0, 0);
            }
        }
        __syncthreads();   // all A2 reads done before overwriting with A3
        #pragma unroll
        for (int nt = 0; nt < 2; ++nt) {
            int kg = n0w + nt * 16 + lr;        // k index of GEMM3
            float b2 = be2[kg];
            int ks = kg >> 5, kq = (kg & 31) >> 3, j = kg & 7;
            #pragma unroll
            for (int mt = 0; mt < 2; ++mt)
                #pragma unroll
                for (int r = 0; r < 4; ++r) {
                    short v = (short)f2bf(sp(acc2[mt][nt][r] + b2));
                    frag_s[fragOff(ks, mt, kq * 16 + quad * 4 + r) + j] = v;
                }
        }
    }
    __syncthreads();

    // ---- P6: GEMM3 (M=32, N=128, K=128) + bias + atomic scatter
    {
        f32x4 acc3[2][2];
        #pragma unroll
        for (int mt = 0; mt < 2; ++mt)
            #pragma unroll
            for (int nt = 0; nt < 2; ++nt) acc3[mt][nt] = zero4;
        for (int ks = 0; ks < 4; ++ks) {
            bf16x8 af0 = *(const bf16x8*)&frag_s[fragOff(ks, 0, lane)];
            bf16x8 af1 = *(const bf16x8*)&frag_s[fragOff(ks, 1, lane)];
            int krow = ks * 32 + quad * 8;
            #pragma unroll
            for (int nt = 0; nt < 2; ++nt) {
                int n = n0w + nt * 16 + lr;
                bf16x8 bw = *(const bf16x8*)&We3T[n * KP2 + krow];
                acc3[0][nt] = __builtin_amdgcn_mfma_f32_16x16x32_bf16(af0, bw, acc3[0][nt], 0, 0, 0);
                acc3[1][nt] = __builtin_amdgcn_mfma_f32_16x16x32_bf16(af1, bw, acc3[1][nt], 0, 0, 0);
            }
        }
        #pragma unroll
        for (int nt = 0; nt < 2; ++nt) {
            int n = n0w + nt * 16 + lr;
            float b3 = be3[n];
            #pragma unroll
            for (int mt = 0; mt < 2; ++mt)
                #pragma unroll
                for (int r = 0; r < 4; ++r) {
                    int m = mt * 16 + quad * 4 + r;
                    atomAddF(&mh[(size_t)dst_s[m] * HID + n], acc3[mt][nt][r] + b3);
                }
        }
    }
    // ---- P7: m_v / cnt atomics
    if (tid < TE) {
        int d = dst_s[tid];
        float w = vw_s[tid];
        atomAddF(&mv[2 * d],     w * rel_s[2 * tid]);
        atomAddF(&mv[2 * d + 1], w * rel_s[2 * tid + 1]);
        atomAddF(&cnt[d], 1.0f);
    }
}

// ---------------------------------------------------------------- node kernel
__global__ __launch_bounds__(256)
void eg_node(const float* __restrict__ x,
             const float* __restrict__ Wh1, const float* __restrict__ bh1,
             const float* __restrict__ gh1, const float* __restrict__ bth1,
             const float* __restrict__ Wh2, const float* __restrict__ bh2,
             const float* __restrict__ mh, const float* __restrict__ mv,
             const float* __restrict__ cnt, float* __restrict__ out)
{
    __shared__ float hin_s[PHIN * NST];
    __shared__ float H_s[HID * NST];
    __shared__ float den_s[TN], mu_s[TN], rs_s[TN];

    const int tid = threadIdx.x;
    const int n_base = blockIdx.x * TN;

    if (tid < TN) {
        int n = n_base + tid;
        float den = 1.f, norm = 0.f;
        if (n < NNODE) {
            den = fmaxf(cnt[n], 1.0f);
            float ax = mv[2 * n] / den + 1e-8f;
            float ay = mv[2 * n + 1] / den + 1e-8f;
            norm = sqrtf(ax * ax + ay * ay);
        }
        den_s[tid] = den;
        hin_s[192 * NST + tid] = norm;
    }
    __syncthreads();
    {
        const int c = tid & 63, ng = tid >> 6;
        #pragma unroll
        for (int it = 0; it < 8; ++it) {
            int nl = it * 4 + ng;
            int n = n_base + nl;
            hin_s[c * NST + nl] = (n < NNODE) ? x[(size_t)n * NCH + c] : 0.f;
        }
        const int k = tid & 127, ng2 = tid >> 7;
        #pragma unroll
        for (int it = 0; it < 16; ++it) {
            int nl = it * 2 + ng2;
            int n = n_base + nl;
            hin_s[(NCH + k) * NST + nl] =
                (n < NNODE) ? mh[(size_t)n * HID + k] / den_s[nl] : 0.f;
        }
    }
    __syncthreads();

    const int n0 = (tid & 7) * 4;
    const int j0 = (tid >> 3) * 4;

    {
        float acc[4][4] = {};
        for (int k = 0; k < PHIN; ++k) {
            const float4 a = *(const float4*)&hin_s[k * NST + n0];
            const float4 wb = *(const float4*)(Wh1 + (size_t)k * HID + j0);
            const float w[4] = { wb.x, wb.y, wb.z, wb.w };
            const float aa[4] = { a.x, a.y, a.z, a.w };
            #pragma unroll
            for (int i = 0; i < 4; ++i)
                #pragma unroll
                for (int j = 0; j < 4; ++j) acc[i][j] += aa[i] * w[j];
        }
        #pragma unroll
        for (int j = 0; j < 4; ++j) {
            float b = bh1[j0 + j];
            #pragma unroll
            for (int i = 0; i < 4; ++i)
                H_s[(j0 + j) * NST + n0 + i] = acc[i][j] + b;
        }
    }
    __syncthreads();

    if (tid < TN) {
        float sum = 0.f, sq = 0.f;
        for (int k = 0; k < HID; ++k) {
            float v = H_s[k * NST + tid];
            sum += v; sq += v * v;
        }
        float mu = sum * (1.0f / HID);
        float var = sq * (1.0f / HID) - mu * mu;
        mu_s[tid] = mu;
        rs_s[tid] = rsqrtf(var + LN_EPS);
    }
    __syncthreads();
    {
        const int nl = tid & 31;
        const int jb = (tid >> 5) * 16;
        const float mu = mu_s[nl], rs = rs_s[nl];
        for (int jj = 0; jj < 16; ++jj) {
            int j = jb + jj;
            float v = H_s[j * NST + nl];
            v = (v - mu) * rs * gh1[j] + bth1[j];
            H_s[j * NST + nl] = sp(v);
        }
    }
    __syncthreads();

    {
        const int o0 = (tid >> 3) * 2;
        float acc[4][2] = {};
        for (int k = 0; k < HID; ++k) {
            const float4 a = *(const float4*)&H_s[k * NST + n0];
            const float2 wb = *(const float2*)(Wh2 + (size_t)k * OUTC + o0);
            const float aa[4] = { a.x, a.y, a.z, a.w };
            #pragma unroll
            for (int i = 0; i < 4; ++i) {
                acc[i][0] += aa[i] * wb.x;
                acc[i][1] += aa[i] * wb.y;
            }
        }
        #pragma unroll
        for (int jo = 0; jo < 2; ++jo) {
            float bo = bh2[o0 + jo];
            #pragma unroll
            for (int i = 0; i < 4; ++i) {
                int n = n_base + n0 + i;
                if (n < NNODE) {
                    out[(size_t)n * OUTC + o0 + jo] =
                        x[(size_t)n * NCH + o0 + jo] + acc[i][jo] + bo;
                }
            }
        }
    }
}

// ---------------------------------------------------------------- launch
extern "C" void kernel_launch(void* const* d_in, const int* in_sizes, int n_in,
                              void* d_out, int out_size, void* d_ws, size_t ws_size,
                              hipStream_t stream)
{
    const float* x    = (const float*)d_in[0];
    const float* pos  = (const float*)d_in[1];
    const float* vel  = (const float*)d_in[2];
    const float* We1  = (const float*)d_in[3];
    const float* be1  = (const float*)d_in[4];
    const float* ge1  = (const float*)d_in[5];
    const float* bte1 = (const float*)d_in[6];
    const float* We2  = (const float*)d_in[7];
    const float* be2  = (const float*)d_in[8];
    const float* We3  = (const float*)d_in[9];
    const float* be3  = (const float*)d_in[10];
    const float* Wv1  = (const float*)d_in[11];
    const float* bv1  = (const float*)d_in[12];
    const float* gv1  = (const float*)d_in[13];
    const float* btv1 = (const float*)d_in[14];
    const float* Wv2  = (const float*)d_in[15];
    const float* bv2  = (const float*)d_in[16];
    const float* Wh1  = (const float*)d_in[17];
    const float* bh1  = (const float*)d_in[18];
    const float* gh1  = (const float*)d_in[19];
    const float* bth1 = (const float*)d_in[20];
    const float* Wh2  = (const float*)d_in[21];
    const float* bh2  = (const float*)d_in[22];
    const int*   ei   = (const int*)d_in[23];

    float* mh  = (float*)d_ws;
    float* mv  = mh + (size_t)NNODE * HID;
    float* cnt = mv + (size_t)NNODE * 2;
    short* wt  = (short*)(((float*)d_ws) + WS_WFLOAT);

    size_t zbytes = (size_t)WS_WFLOAT * sizeof(float);
    hipMemsetAsync(d_ws, 0, zbytes, stream);

    eg_prep<<<dim3((WT_TOTAL + 255) / 256), dim3(256), 0, stream>>>(We1, Wv1, We2, We3, wt);

    eg_edge<<<dim3(NEDGE / TE), dim3(256), 0, stream>>>(
        x, pos, vel, be1, ge1, bte1, be2, be3,
        bv1, gv1, btv1, Wv2, bv2, wt, ei, mh, mv, cnt);

    eg_node<<<dim3((NNODE + TN - 1) / TN), dim3(256), 0, stream>>>(
        x, Wh1, bh1, gh1, bth1, Wh2, bh2, mh, mv, cnt, (float*)d_out);
}

// Round 4
// 621.109 us; speedup vs baseline: 4.1474x; 1.5788x over previous
//
#include <hip/hip_runtime.h>
#include <stdint.h>

#define NCH    64
#define HID    128
#define OUTC   64
#define NNODE  20000
#define NEDGE  640000
#define FDIM   133
#define PHIN   193
#define TE     32
#define TN     32
#define NST    36
#define LN_EPS 1e-5f
#define KP1    160          // K of GEMM1, padded (133 -> 160 = 5*32)
#define KP2    128          // K of GEMM2/3
#define CSTR   132          // fp32 C buffer row stride (dwords)

typedef __attribute__((ext_vector_type(8))) short bf16x8;
typedef __attribute__((ext_vector_type(4))) float f32x4;

__device__ __forceinline__ unsigned short f2bf(float f) {
    union { float f; unsigned int i; } v; v.f = f;
    unsigned int b = v.i;
    return (unsigned short)((b + 0x7FFFu + ((b >> 16) & 1u)) >> 16);
}
// fast softplus: hardware v_exp_f32 / v_log_f32 via __expf/__logf.
// log(1+y) direct is fine: for y<1e-7 the absolute error is ~1e-7.
__device__ __forceinline__ float sp(float xv) {
    return fmaxf(xv, 0.f) + __logf(1.0f + __expf(-fabsf(xv)));
}
__device__ __forceinline__ void atomAddF(float* p, float v) {
    __hip_atomic_fetch_add(p, v, __ATOMIC_RELAXED, __HIP_MEMORY_SCOPE_AGENT);
}
// A/B fragment offset in a [kstep][mtile(2)][lane(64)][8] bf16 buffer
__device__ __forceinline__ int fragOff(int ks, int mt, int lanepos) {
    return ((ks * 2 + mt) * 64 + lanepos) * 8;
}

// Workspace layout (floats): mh[20000*128] mv[20000*2] cnt[20000], then bf16 WT
#define WS_WFLOAT (NNODE * HID + NNODE * 2 + NNODE)   // 2,620,000 floats
#define WT_WE1 0
#define WT_WV1 (128 * KP1)
#define WT_WE2 (2 * 128 * KP1)
#define WT_WE3 (2 * 128 * KP1 + 128 * KP2)
#define WT_TOTAL (2 * 128 * KP1 + 2 * 128 * KP2)      // 73728 shorts

// ------------------------------------------------- weight transpose/convert
__global__ __launch_bounds__(256)
void eg_prep(const float* __restrict__ We1, const float* __restrict__ Wv1,
             const float* __restrict__ We2, const float* __restrict__ We3,
             short* __restrict__ wt)
{
    int idx = blockIdx.x * 256 + threadIdx.x;
    if (idx >= WT_TOTAL) return;
    if (idx < WT_WV1) {
        int n = idx / KP1, k = idx % KP1;
        wt[idx] = (k < FDIM) ? (short)f2bf(We1[(size_t)k * HID + n]) : (short)0;
    } else if (idx < WT_WE2) {
        int r = idx - WT_WV1; int n = r / KP1, k = r % KP1;
        wt[idx] = (k < FDIM) ? (short)f2bf(Wv1[(size_t)k * HID + n]) : (short)0;
    } else if (idx < WT_WE3) {
        int r = idx - WT_WE2; int n = r / KP2, k = r % KP2;
        wt[idx] = (short)f2bf(We2[(size_t)k * HID + n]);
    } else {
        int r = idx - WT_WE3; int n = r / KP2, k = r % KP2;
        wt[idx] = (short)f2bf(We3[(size_t)k * HID + n]);
    }
}

// ---------------------------------------------------------------- edge kernel
__global__ __launch_bounds__(256)
void eg_edge(const float* __restrict__ x, const float* __restrict__ pos,
             const float* __restrict__ vel,
             const float* __restrict__ be1, const float* __restrict__ ge1,
             const float* __restrict__ bte1, const float* __restrict__ be2,
             const float* __restrict__ be3,
             const float* __restrict__ bv1, const float* __restrict__ gv1,
             const float* __restrict__ btv1,
             const float* __restrict__ Wv2, const float* __restrict__ bv2,
             const short* __restrict__ wt,
             const int* __restrict__ ei,
             float* __restrict__ mh, float* __restrict__ mv,
             float* __restrict__ cnt)
{
    __shared__ __align__(16) short frag_s[5 * 2 * 64 * 8];   // 10240 B
    __shared__ __align__(16) float C_s[2 * TE * CSTR];        // 33792 B
    __shared__ float psum_s[512], psq_s[512];                 // 4096 B
    __shared__ float mu_s[64], rs_s[64];
    __shared__ int   dst_s[TE], src_s[TE];
    __shared__ float rel_s[TE * 2], vw_s[TE];

    const int tid  = threadIdx.x;
    const int lane = tid & 63;
    const int wid  = tid >> 6;
    const int lr   = lane & 15;
    const int quad = lane >> 4;
    const int n0w  = wid * 32;
    const int e_base = blockIdx.x * TE;

    const short* We1T = wt + WT_WE1;
    const short* Wv1T = wt + WT_WV1;
    const short* We2T = wt + WT_WE2;
    const short* We3T = wt + WT_WE3;

    // ---- P0: indices + geometry (regs), zero kstep-4 frag region
    float geo[5];
    if (tid < TE) {
        int gi = e_base + tid;
        int eS = ei[gi];
        int eD = ei[NEDGE + gi];
        src_s[tid] = eS; dst_s[tid] = eD;
        float rx = pos[2 * eS]     - pos[2 * eD];
        float ry = pos[2 * eS + 1] - pos[2 * eD + 1];
        float vx = vel[2 * eS]     - vel[2 * eD];
        float vy = vel[2 * eS + 1] - vel[2 * eD + 1];
        float dsq = rx * rx + ry * ry;
        float dvr = vx * rx + vy * ry;
        float r2  = fminf(1.0f / (dsq + 0.05f), 20.0f);
        float r6  = fminf(r2 * r2 * r2, 400.0f);
        float r12 = fminf(r6 * r6, 160000.0f);
        geo[0] = dsq; geo[1] = dvr; geo[2] = r2; geo[3] = r6; geo[4] = r12;
        rel_s[2 * tid] = rx; rel_s[2 * tid + 1] = ry;
    }
    if (tid < 128) {   // zero kstep 4 region
        int4 z = {0, 0, 0, 0};
        *(int4*)&frag_s[4 * 2 * 64 * 8 + tid * 8] = z;
    }
    __syncthreads();

    // ---- P1: geo shorts + gather x into A1 fragments (bf16)
    if (tid < TE) {
        int off = fragOff(4, tid >> 4, (tid & 15));
        #pragma unroll
        for (int j = 0; j < 5; ++j) frag_s[off + j] = (short)f2bf(geo[j]);
    }
    {
        const int e = tid & 31, slot = tid >> 5;
        const int d = dst_s[e], s = src_s[e];
        #pragma unroll
        for (int h = 0; h < 2; ++h) {
            int o = slot + h * 8;
            int node = h ? s : d;
            int c0 = (o & 7) * 8;
            const float4 a0 = *(const float4*)&x[(size_t)node * NCH + c0];
            const float4 a1 = *(const float4*)&x[(size_t)node * NCH + c0 + 4];
            bf16x8 v;
            v[0] = (short)f2bf(a0.x); v[1] = (short)f2bf(a0.y);
            v[2] = (short)f2bf(a0.z); v[3] = (short)f2bf(a0.w);
            v[4] = (short)f2bf(a1.x); v[5] = (short)f2bf(a1.y);
            v[6] = (short)f2bf(a1.z); v[7] = (short)f2bf(a1.w);
            int ks = o >> 2, kq = o & 3;
            *(bf16x8*)&frag_s[fragOff(ks, e >> 4, kq * 16 + (e & 15))] = v;
        }
    }
    __syncthreads();

    // ---- P2: dual GEMM1 via MFMA (M=32, N=128, K=160)
    f32x4 zero4 = {0.f, 0.f, 0.f, 0.f};
    {
        f32x4 accE[2][2], accV[2][2];
        #pragma unroll
        for (int mt = 0; mt < 2; ++mt)
            #pragma unroll
            for (int nt = 0; nt < 2; ++nt) { accE[mt][nt] = zero4; accV[mt][nt] = zero4; }
        for (int ks = 0; ks < 5; ++ks) {
            bf16x8 af0 = *(const bf16x8*)&frag_s[fragOff(ks, 0, lane)];
            bf16x8 af1 = *(const bf16x8*)&frag_s[fragOff(ks, 1, lane)];
            int krow = ks * 32 + quad * 8;
            #pragma unroll
            for (int nt = 0; nt < 2; ++nt) {
                int n = n0w + nt * 16 + lr;
                bf16x8 bwE = *(const bf16x8*)&We1T[n * KP1 + krow];
                bf16x8 bwV = *(const bf16x8*)&Wv1T[n * KP1 + krow];
                accE[0][nt] = __builtin_amdgcn_mfma_f32_16x16x32_bf16(af0, bwE, accE[0][nt], 0, 0, 0);
                accE[1][nt] = __builtin_amdgcn_mfma_f32_16x16x32_bf16(af1, bwE, accE[1][nt], 0, 0, 0);
                accV[0][nt] = __builtin_amdgcn_mfma_f32_16x16x32_bf16(af0, bwV, accV[0][nt], 0, 0, 0);
                accV[1][nt] = __builtin_amdgcn_mfma_f32_16x16x32_bf16(af1, bwV, accV[1][nt], 0, 0, 0);
            }
        }
        #pragma unroll
        for (int nt = 0; nt < 2; ++nt) {
            int n = n0w + nt * 16 + lr;
            float be = be1[n], bv = bv1[n];
            #pragma unroll
            for (int mt = 0; mt < 2; ++mt)
                #pragma unroll
                for (int r = 0; r < 4; ++r) {
                    int row = mt * 16 + quad * 4 + r;
                    C_s[row * CSTR + n]             = accE[mt][nt][r] + be;
                    C_s[TE * CSTR + row * CSTR + n] = accV[mt][nt][r] + bv;
                }
        }
    }
    __syncthreads();

    // ---- P3: LN partial stats (both paths), vectorized reads
    {
        const int e = tid & 31, seg = tid >> 5;
        const float4 u0 = *(const float4*)&C_s[e * CSTR + seg * 16];
        const float4 u1 = *(const float4*)&C_s[e * CSTR + seg * 16 + 4];
        const float4 u2 = *(const float4*)&C_s[e * CSTR + seg * 16 + 8];
        const float4 u3 = *(const float4*)&C_s[e * CSTR + seg * 16 + 12];
        const float4 w0 = *(const float4*)&C_s[TE * CSTR + e * CSTR + seg * 16];
        const float4 w1 = *(const float4*)&C_s[TE * CSTR + e * CSTR + seg * 16 + 4];
        const float4 w2 = *(const float4*)&C_s[TE * CSTR + e * CSTR + seg * 16 + 8];
        const float4 w3 = *(const float4*)&C_s[TE * CSTR + e * CSTR + seg * 16 + 12];
        float s0 = 0.f, q0 = 0.f, s1 = 0.f, q1 = 0.f;
        const float uu[16] = { u0.x,u0.y,u0.z,u0.w, u1.x,u1.y,u1.z,u1.w,
                               u2.x,u2.y,u2.z,u2.w, u3.x,u3.y,u3.z,u3.w };
        const float ww[16] = { w0.x,w0.y,w0.z,w0.w, w1.x,w1.y,w1.z,w1.w,
                               w2.x,w2.y,w2.z,w2.w, w3.x,w3.y,w3.z,w3.w };
        #pragma unroll
        for (int j = 0; j < 16; ++j) {
            s0 += uu[j]; q0 += uu[j] * uu[j];
            s1 += ww[j]; q1 += ww[j] * ww[j];
        }
        psum_s[e * 8 + seg] = s0;       psq_s[e * 8 + seg] = q0;
        psum_s[256 + e * 8 + seg] = s1; psq_s[256 + e * 8 + seg] = q1;
    }
    __syncthreads();
    if (tid < 64) {
        int p = tid >> 5, e = tid & 31;
        float s = 0.f, q = 0.f;
        #pragma unroll
        for (int g = 0; g < 8; ++g) { s += psum_s[p * 256 + e * 8 + g]; q += psq_s[p * 256 + e * 8 + g]; }
        float mu = s * (1.0f / HID);
        float var = q * (1.0f / HID) - mu * mu;
        mu_s[p * 32 + e] = mu;
        rs_s[p * 32 + e] = rsqrtf(var + LN_EPS);
    }
    __syncthreads();

    // ---- P4a: h-path LN+softplus -> bf16 A2 fragments
    #pragma unroll
    for (int it = 0; it < 2; ++it) {
        int item = tid + it * 256;
        int e = item & 31, o = item >> 5;
        float mu = mu_s[e], rs = rs_s[e];
        const float4 v0 = *(const float4*)&C_s[e * CSTR + o * 8];
        const float4 v1 = *(const float4*)&C_s[e * CSTR + o * 8 + 4];
        const float4 g0 = *(const float4*)&ge1[o * 8];
        const float4 g1 = *(const float4*)&ge1[o * 8 + 4];
        const float4 t0 = *(const float4*)&bte1[o * 8];
        const float4 t1 = *(const float4*)&bte1[o * 8 + 4];
        float vv[8] = { v0.x, v0.y, v0.z, v0.w, v1.x, v1.y, v1.z, v1.w };
        float gg[8] = { g0.x, g0.y, g0.z, g0.w, g1.x, g1.y, g1.z, g1.w };
        float tt[8] = { t0.x, t0.y, t0.z, t0.w, t1.x, t1.y, t1.z, t1.w };
        bf16x8 outv;
        #pragma unroll
        for (int j = 0; j < 8; ++j)
            outv[j] = (short)f2bf(sp((vv[j] - mu) * rs * gg[j] + tt[j]));
        *(bf16x8*)&frag_s[fragOff(o >> 2, e >> 4, (o & 3) * 16 + (e & 15))] = outv;
    }
    // ---- P4b: v-path LN+softplus+dot(Wv2) partials, vectorized
    {
        const int e = tid & 31, seg = tid >> 5;
        float mu = mu_s[32 + e], rs = rs_s[32 + e];
        const float4 c0 = *(const float4*)&C_s[TE * CSTR + e * CSTR + seg * 16];
        const float4 c1 = *(const float4*)&C_s[TE * CSTR + e * CSTR + seg * 16 + 4];
        const float4 c2 = *(const float4*)&C_s[TE * CSTR + e * CSTR + seg * 16 + 8];
        const float4 c3 = *(const float4*)&C_s[TE * CSTR + e * CSTR + seg * 16 + 12];
        float cc[16] = { c0.x,c0.y,c0.z,c0.w, c1.x,c1.y,c1.z,c1.w,
                         c2.x,c2.y,c2.z,c2.w, c3.x,c3.y,c3.z,c3.w };
        float acc = 0.f;
        #pragma unroll
        for (int jj = 0; jj < 16; ++jj) {
            int j = seg * 16 + jj;
            float v = (cc[jj] - mu) * rs * gv1[j] + btv1[j];
            acc += sp(v) * Wv2[j];
        }
        psum_s[seg * 32 + e] = acc;
    }
    __syncthreads();
    if (tid < TE) {
        float s = 0.f;
        #pragma unroll
        for (int g = 0; g < 8; ++g) s += psum_s[g * 32 + tid];
        vw_s[tid] = s + bv2[0];
    }

    // ---- P5: GEMM2 (M=32, N=128, K=128) + softplus -> A3 fragments
    {
        f32x4 acc2[2][2];
        #pragma unroll
        for (int mt = 0; mt < 2; ++mt)
            #pragma unroll
            for (int nt = 0; nt < 2; ++nt) acc2[mt][nt] = zero4;
        for (int ks = 0; ks < 4; ++ks) {
            bf16x8 af0 = *(const bf16x8*)&frag_s[fragOff(ks, 0, lane)];
            bf16x8 af1 = *(const bf16x8*)&frag_s[fragOff(ks, 1, lane)];
            int krow = ks * 32 + quad * 8;
            #pragma unroll
            for (int nt = 0; nt < 2; ++nt) {
                int n = n0w + nt * 16 + lr;
                bf16x8 bw = *(const bf16x8*)&We2T[n * KP2 + krow];
                acc2[0][nt] = __builtin_amdgcn_mfma_f32_16x16x32_bf16(af0, bw, acc2[0][nt], 0, 0, 0);
                acc2[1][nt] = __builtin_amdgcn_mfma_f32_16x16x32_bf16(af1, bw, acc2[1][nt], 0, 0, 0);
            }
        }
        __syncthreads();
        #pragma unroll
        for (int nt = 0; nt < 2; ++nt) {
            int kg = n0w + nt * 16 + lr;
            float b2 = be2[kg];
            int ks = kg >> 5, kq = (kg & 31) >> 3, j = kg & 7;
            #pragma unroll
            for (int mt = 0; mt < 2; ++mt)
                #pragma unroll
                for (int r = 0; r < 4; ++r) {
                    short v = (short)f2bf(sp(acc2[mt][nt][r] + b2));
                    frag_s[fragOff(ks, mt, kq * 16 + quad * 4 + r) + j] = v;
                }
        }
    }
    __syncthreads();

    // ---- P6: GEMM3 (M=32, N=128, K=128) + bias + atomic scatter
    {
        f32x4 acc3[2][2];
        #pragma unroll
        for (int mt = 0; mt < 2; ++mt)
            #pragma unroll
            for (int nt = 0; nt < 2; ++nt) acc3[mt][nt] = zero4;
        for (int ks = 0; ks < 4; ++ks) {
            bf16x8 af0 = *(const bf16x8*)&frag_s[fragOff(ks, 0, lane)];
            bf16x8 af1 = *(const bf16x8*)&frag_s[fragOff(ks, 1, lane)];
            int krow = ks * 32 + quad * 8;
            #pragma unroll
            for (int nt = 0; nt < 2; ++nt) {
                int n = n0w + nt * 16 + lr;
                bf16x8 bw = *(const bf16x8*)&We3T[n * KP2 + krow];
                acc3[0][nt] = __builtin_amdgcn_mfma_f32_16x16x32_bf16(af0, bw, acc3[0][nt], 0, 0, 0);
                acc3[1][nt] = __builtin_amdgcn_mfma_f32_16x16x32_bf16(af1, bw, acc3[1][nt], 0, 0, 0);
            }
        }
        #pragma unroll
        for (int nt = 0; nt < 2; ++nt) {
            int n = n0w + nt * 16 + lr;
            float b3 = be3[n];
            #pragma unroll
            for (int mt = 0; mt < 2; ++mt)
                #pragma unroll
                for (int r = 0; r < 4; ++r) {
                    int m = mt * 16 + quad * 4 + r;
                    atomAddF(&mh[(size_t)dst_s[m] * HID + n], acc3[mt][nt][r] + b3);
                }
        }
    }
    // ---- P7: m_v / cnt atomics
    if (tid < TE) {
        int d = dst_s[tid];
        float w = vw_s[tid];
        atomAddF(&mv[2 * d],     w * rel_s[2 * tid]);
        atomAddF(&mv[2 * d + 1], w * rel_s[2 * tid + 1]);
        atomAddF(&cnt[d], 1.0f);
    }
}

// ---------------------------------------------------------------- node kernel
__global__ __launch_bounds__(256)
void eg_node(const float* __restrict__ x,
             const float* __restrict__ Wh1, const float* __restrict__ bh1,
             const float* __restrict__ gh1, const float* __restrict__ bth1,
             const float* __restrict__ Wh2, const float* __restrict__ bh2,
             const float* __restrict__ mh, const float* __restrict__ mv,
             const float* __restrict__ cnt, float* __restrict__ out)
{
    __shared__ float hin_s[PHIN * NST];
    __shared__ float H_s[HID * NST];
    __shared__ float den_s[TN], mu_s[TN], rs_s[TN];

    const int tid = threadIdx.x;
    const int n_base = blockIdx.x * TN;

    if (tid < TN) {
        int n = n_base + tid;
        float den = 1.f, norm = 0.f;
        if (n < NNODE) {
            den = fmaxf(cnt[n], 1.0f);
            float ax = mv[2 * n] / den + 1e-8f;
            float ay = mv[2 * n + 1] / den + 1e-8f;
            norm = sqrtf(ax * ax + ay * ay);
        }
        den_s[tid] = den;
        hin_s[192 * NST + tid] = norm;
    }
    __syncthreads();
    {
        const int c = tid & 63, ng = tid >> 6;
        #pragma unroll
        for (int it = 0; it < 8; ++it) {
            int nl = it * 4 + ng;
            int n = n_base + nl;
            hin_s[c * NST + nl] = (n < NNODE) ? x[(size_t)n * NCH + c] : 0.f;
        }
        const int k = tid & 127, ng2 = tid >> 7;
        #pragma unroll
        for (int it = 0; it < 16; ++it) {
            int nl = it * 2 + ng2;
            int n = n_base + nl;
            hin_s[(NCH + k) * NST + nl] =
                (n < NNODE) ? mh[(size_t)n * HID + k] / den_s[nl] : 0.f;
        }
    }
    __syncthreads();

    const int n0 = (tid & 7) * 4;
    const int j0 = (tid >> 3) * 4;

    {
        float acc[4][4] = {};
        for (int k = 0; k < PHIN; ++k) {
            const float4 a = *(const float4*)&hin_s[k * NST + n0];
            const float4 wb = *(const float4*)(Wh1 + (size_t)k * HID + j0);
            const float w[4] = { wb.x, wb.y, wb.z, wb.w };
            const float aa[4] = { a.x, a.y, a.z, a.w };
            #pragma unroll
            for (int i = 0; i < 4; ++i)
                #pragma unroll
                for (int j = 0; j < 4; ++j) acc[i][j] += aa[i] * w[j];
        }
        #pragma unroll
        for (int j = 0; j < 4; ++j) {
            float b = bh1[j0 + j];
            #pragma unroll
            for (int i = 0; i < 4; ++i)
                H_s[(j0 + j) * NST + n0 + i] = acc[i][j] + b;
        }
    }
    __syncthreads();

    if (tid < TN) {
        float sum = 0.f, sq = 0.f;
        for (int k = 0; k < HID; ++k) {
            float v = H_s[k * NST + tid];
            sum += v; sq += v * v;
        }
        float mu = sum * (1.0f / HID);
        float var = sq * (1.0f / HID) - mu * mu;
        mu_s[tid] = mu;
        rs_s[tid] = rsqrtf(var + LN_EPS);
    }
    __syncthreads();
    {
        const int nl = tid & 31;
        const int jb = (tid >> 5) * 16;
        const float mu = mu_s[nl], rs = rs_s[nl];
        for (int jj = 0; jj < 16; ++jj) {
            int j = jb + jj;
            float v = H_s[j * NST + nl];
            v = (v - mu) * rs * gh1[j] + bth1[j];
            H_s[j * NST + nl] = sp(v);
        }
    }
    __syncthreads();

    {
        const int o0 = (tid >> 3) * 2;
        float acc[4][2] = {};
        for (int k = 0; k < HID; ++k) {
            const float4 a = *(const float4*)&H_s[k * NST + n0];
            const float2 wb = *(const float2*)(Wh2 + (size_t)k * OUTC + o0);
            const float aa[4] = { a.x, a.y, a.z, a.w };
            #pragma unroll
            for (int i = 0; i < 4; ++i) {
                acc[i][0] += aa[i] * wb.x;
                acc[i][1] += aa[i] * wb.y;
            }
        }
        #pragma unroll
        for (int jo = 0; jo < 2; ++jo) {
            float bo = bh2[o0 + jo];
            #pragma unroll
            for (int i = 0; i < 4; ++i) {
                int n = n_base + n0 + i;
                if (n < NNODE) {
                    out[(size_t)n * OUTC + o0 + jo] =
                        x[(size_t)n * NCH + o0 + jo] + acc[i][jo] + bo;
                }
            }
        }
    }
}

// ---------------------------------------------------------------- launch
extern "C" void kernel_launch(void* const* d_in, const int* in_sizes, int n_in,
                              void* d_out, int out_size, void* d_ws, size_t ws_size,
                              hipStream_t stream)
{
    const float* x    = (const float*)d_in[0];
    const float* pos  = (const float*)d_in[1];
    const float* vel  = (const float*)d_in[2];
    const float* We1  = (const float*)d_in[3];
    const float* be1  = (const float*)d_in[4];
    const float* ge1  = (const float*)d_in[5];
    const float* bte1 = (const float*)d_in[6];
    const float* We2  = (const float*)d_in[7];
    const float* be2  = (const float*)d_in[8];
    const float* We3  = (const float*)d_in[9];
    const float* be3  = (const float*)d_in[10];
    const float* Wv1  = (const float*)d_in[11];
    const float* bv1  = (const float*)d_in[12];
    const float* gv1  = (const float*)d_in[13];
    const float* btv1 = (const float*)d_in[14];
    const float* Wv2  = (const float*)d_in[15];
    const float* bv2  = (const float*)d_in[16];
    const float* Wh1  = (const float*)d_in[17];
    const float* bh1  = (const float*)d_in[18];
    const float* gh1  = (const float*)d_in[19];
    const float* bth1 = (const float*)d_in[20];
    const float* Wh2  = (const float*)d_in[21];
    const float* bh2  = (const float*)d_in[22];
    const int*   ei   = (const int*)d_in[23];

    float* mh  = (float*)d_ws;
    float* mv  = mh + (size_t)NNODE * HID;
    float* cnt = mv + (size_t)NNODE * 2;
    short* wt  = (short*)(((float*)d_ws) + WS_WFLOAT);

    size_t zbytes = (size_t)WS_WFLOAT * sizeof(float);
    hipMemsetAsync(d_ws, 0, zbytes, stream);

    eg_prep<<<dim3((WT_TOTAL + 255) / 256), dim3(256), 0, stream>>>(We1, Wv1, We2, We3, wt);

    eg_edge<<<dim3(NEDGE / TE), dim3(256), 0, stream>>>(
        x, pos, vel, be1, ge1, bte1, be2, be3,
        bv1, gv1, btv1, Wv2, bv2, wt, ei, mh, mv, cnt);

    eg_node<<<dim3((NNODE + TN - 1) / TN), dim3(256), 0, stream>>>(
        x, Wh1, bh1, gh1, bth1, Wh2, bh2, mh, mv, cnt, (float*)d_out);
}

// Round 5
// 618.352 us; speedup vs baseline: 4.1659x; 1.0045x over previous
//
#include <hip/hip_runtime.h>
#include <stdint.h>

#define NCH    64
#define HID    128
#define OUTC   64
#define NNODE  20000
#define NEDGE  640000
#define FDIM   133
#define PHIN   193
#define TE     32
#define TN     32
#define NST    36
#define LN_EPS 1e-5f
#define KP1    160          // K of GEMM1, padded (133 -> 160 = 5*32)
#define KP2    128          // K of GEMM2/3

typedef __attribute__((ext_vector_type(8))) short bf16x8;
typedef __attribute__((ext_vector_type(4))) float f32x4;

__device__ __forceinline__ unsigned short f2bf(float f) {
    union { float f; unsigned int i; } v; v.f = f;
    unsigned int b = v.i;
    return (unsigned short)((b + 0x7FFFu + ((b >> 16) & 1u)) >> 16);
}
// fast softplus: hardware v_exp_f32 / v_log_f32
__device__ __forceinline__ float sp(float xv) {
    return fmaxf(xv, 0.f) + __logf(1.0f + __expf(-fabsf(xv)));
}
__device__ __forceinline__ void atomAddF(float* p, float v) {
    __hip_atomic_fetch_add(p, v, __ATOMIC_RELAXED, __HIP_MEMORY_SCOPE_AGENT);
}
// A/B fragment offset in a [kstep][mtile(2)][lane(64)][8] bf16 buffer
__device__ __forceinline__ int fragOff(int ks, int mt, int lanepos) {
    return ((ks * 2 + mt) * 64 + lanepos) * 8;
}

// Workspace layout (floats): mh[20000*128] mv[20000*2] cnt[20000], then bf16 WT
#define WS_WFLOAT (NNODE * HID + NNODE * 2 + NNODE)   // 2,620,000 floats
#define WT_WE1 0
#define WT_WV1 (128 * KP1)
#define WT_WE2 (2 * 128 * KP1)
#define WT_WE3 (2 * 128 * KP1 + 128 * KP2)
#define WT_TOTAL (2 * 128 * KP1 + 2 * 128 * KP2)      // 73728 shorts

// ------------------------------------------------- weight transpose/convert
__global__ __launch_bounds__(256)
void eg_prep(const float* __restrict__ We1, const float* __restrict__ Wv1,
             const float* __restrict__ We2, const float* __restrict__ We3,
             short* __restrict__ wt)
{
    int idx = blockIdx.x * 256 + threadIdx.x;
    if (idx >= WT_TOTAL) return;
    if (idx < WT_WV1) {
        int n = idx / KP1, k = idx % KP1;
        wt[idx] = (k < FDIM) ? (short)f2bf(We1[(size_t)k * HID + n]) : (short)0;
    } else if (idx < WT_WE2) {
        int r = idx - WT_WV1; int n = r / KP1, k = r % KP1;
        wt[idx] = (k < FDIM) ? (short)f2bf(Wv1[(size_t)k * HID + n]) : (short)0;
    } else if (idx < WT_WE3) {
        int r = idx - WT_WE2; int n = r / KP2, k = r % KP2;
        wt[idx] = (short)f2bf(We2[(size_t)k * HID + n]);
    } else {
        int r = idx - WT_WE3; int n = r / KP2, k = r % KP2;
        wt[idx] = (short)f2bf(We3[(size_t)k * HID + n]);
    }
}

// ---------------------------------------------------------------- edge kernel
__global__ __launch_bounds__(256, 6)
void eg_edge(const float* __restrict__ x, const float* __restrict__ pos,
             const float* __restrict__ vel,
             const float* __restrict__ be1, const float* __restrict__ ge1,
             const float* __restrict__ bte1, const float* __restrict__ be2,
             const float* __restrict__ be3,
             const float* __restrict__ bv1, const float* __restrict__ gv1,
             const float* __restrict__ btv1,
             const float* __restrict__ Wv2, const float* __restrict__ bv2,
             const short* __restrict__ wt,
             const int* __restrict__ ei,
             float* __restrict__ mh, float* __restrict__ mv,
             float* __restrict__ cnt)
{
    __shared__ __align__(16) short frag_s[5 * 2 * 64 * 8];   // 10240 B
    __shared__ float psum_s[512];                             // 2048 B
    __shared__ float mu_s[64], rs_s[64];
    __shared__ int   dst_s[TE], src_s[TE];
    __shared__ float rel_s[TE * 2], vw_s[TE];

    const int tid  = threadIdx.x;
    const int lane = tid & 63;
    const int wid  = tid >> 6;
    const int lr   = lane & 15;
    const int quad = lane >> 4;
    const int n0w  = wid * 32;
    const int e_base = blockIdx.x * TE;

    const short* We1T = wt + WT_WE1;
    const short* Wv1T = wt + WT_WV1;
    const short* We2T = wt + WT_WE2;
    const short* We3T = wt + WT_WE3;

    // ---- P0: indices + geometry (regs), zero kstep-4 frag region
    float geo[5];
    if (tid < TE) {
        int gi = e_base + tid;
        int eS = ei[gi];
        int eD = ei[NEDGE + gi];
        src_s[tid] = eS; dst_s[tid] = eD;
        float rx = pos[2 * eS]     - pos[2 * eD];
        float ry = pos[2 * eS + 1] - pos[2 * eD + 1];
        float vx = vel[2 * eS]     - vel[2 * eD];
        float vy = vel[2 * eS + 1] - vel[2 * eD + 1];
        float dsq = rx * rx + ry * ry;
        float dvr = vx * rx + vy * ry;
        float r2  = fminf(1.0f / (dsq + 0.05f), 20.0f);
        float r6  = fminf(r2 * r2 * r2, 400.0f);
        float r12 = fminf(r6 * r6, 160000.0f);
        geo[0] = dsq; geo[1] = dvr; geo[2] = r2; geo[3] = r6; geo[4] = r12;
        rel_s[2 * tid] = rx; rel_s[2 * tid + 1] = ry;
    }
    if (tid < 128) {   // zero kstep 4 region
        int4 z = {0, 0, 0, 0};
        *(int4*)&frag_s[4 * 2 * 64 * 8 + tid * 8] = z;
    }
    __syncthreads();

    // ---- P1: geo shorts + gather x into A1 fragments (bf16)
    if (tid < TE) {
        int off = fragOff(4, tid >> 4, (tid & 15));
        #pragma unroll
        for (int j = 0; j < 5; ++j) frag_s[off + j] = (short)f2bf(geo[j]);
    }
    {
        const int e = tid & 31, slot = tid >> 5;
        const int d = dst_s[e], s = src_s[e];
        #pragma unroll
        for (int h = 0; h < 2; ++h) {
            int o = slot + h * 8;
            int node = h ? s : d;
            int c0 = (o & 7) * 8;
            const float4 a0 = *(const float4*)&x[(size_t)node * NCH + c0];
            const float4 a1 = *(const float4*)&x[(size_t)node * NCH + c0 + 4];
            bf16x8 v;
            v[0] = (short)f2bf(a0.x); v[1] = (short)f2bf(a0.y);
            v[2] = (short)f2bf(a0.z); v[3] = (short)f2bf(a0.w);
            v[4] = (short)f2bf(a1.x); v[5] = (short)f2bf(a1.y);
            v[6] = (short)f2bf(a1.z); v[7] = (short)f2bf(a1.w);
            int ks = o >> 2, kq = o & 3;
            *(bf16x8*)&frag_s[fragOff(ks, e >> 4, kq * 16 + (e & 15))] = v;
        }
    }
    __syncthreads();

    const int ncol0 = n0w + lr;          // nt=0 column
    const int ncol1 = n0w + 16 + lr;     // nt=1 column

    // ---- P2: dual GEMM1 via MFMA (M=32, N=128, K=160), accumulators in regs
    f32x4 zero4 = {0.f, 0.f, 0.f, 0.f};
    f32x4 accE[2][2], accV[2][2];
    #pragma unroll
    for (int mt = 0; mt < 2; ++mt)
        #pragma unroll
        for (int nt = 0; nt < 2; ++nt) { accE[mt][nt] = zero4; accV[mt][nt] = zero4; }
    for (int ks = 0; ks < 5; ++ks) {
        bf16x8 af0 = *(const bf16x8*)&frag_s[fragOff(ks, 0, lane)];
        bf16x8 af1 = *(const bf16x8*)&frag_s[fragOff(ks, 1, lane)];
        int krow = ks * 32 + quad * 8;
        #pragma unroll
        for (int nt = 0; nt < 2; ++nt) {
            int n = n0w + nt * 16 + lr;
            bf16x8 bwE = *(const bf16x8*)&We1T[n * KP1 + krow];
            bf16x8 bwV = *(const bf16x8*)&Wv1T[n * KP1 + krow];
            accE[0][nt] = __builtin_amdgcn_mfma_f32_16x16x32_bf16(af0, bwE, accE[0][nt], 0, 0, 0);
            accE[1][nt] = __builtin_amdgcn_mfma_f32_16x16x32_bf16(af1, bwE, accE[1][nt], 0, 0, 0);
            accV[0][nt] = __builtin_amdgcn_mfma_f32_16x16x32_bf16(af0, bwV, accV[0][nt], 0, 0, 0);
            accV[1][nt] = __builtin_amdgcn_mfma_f32_16x16x32_bf16(af1, bwV, accV[1][nt], 0, 0, 0);
        }
    }
    // bias in-register
    {
        float be0 = be1[ncol0], be_1 = be1[ncol1];
        float bv0 = bv1[ncol0], bv_1 = bv1[ncol1];
        #pragma unroll
        for (int mt = 0; mt < 2; ++mt)
            #pragma unroll
            for (int r = 0; r < 4; ++r) {
                accE[mt][0][r] += be0; accE[mt][1][r] += be_1;
                accV[mt][0][r] += bv0; accV[mt][1][r] += bv_1;
            }
    }

    // ---- P3: LN stats fully in-register (16-lane butterflies over lr)
    #pragma unroll
    for (int mt = 0; mt < 2; ++mt)
        #pragma unroll
        for (int r = 0; r < 4; ++r) {
            float se = accE[mt][0][r] + accE[mt][1][r];
            float qe = accE[mt][0][r] * accE[mt][0][r] + accE[mt][1][r] * accE[mt][1][r];
            float sv = accV[mt][0][r] + accV[mt][1][r];
            float qv = accV[mt][0][r] * accV[mt][0][r] + accV[mt][1][r] * accV[mt][1][r];
            #pragma unroll
            for (int m = 1; m < 16; m <<= 1) {
                se += __shfl_xor(se, m, 16);
                qe += __shfl_xor(qe, m, 16);
                sv += __shfl_xor(sv, m, 16);
                qv += __shfl_xor(qv, m, 16);
            }
            if (lr == 0) {
                int row = mt * 16 + quad * 4 + r;
                psum_s[      row * 4 + wid] = se;
                psum_s[128 + row * 4 + wid] = qe;
                psum_s[256 + row * 4 + wid] = sv;
                psum_s[384 + row * 4 + wid] = qv;
            }
        }
    __syncthreads();
    if (tid < 64) {
        int p = tid >> 5, row = tid & 31;
        float s = 0.f, q = 0.f;
        #pragma unroll
        for (int w = 0; w < 4; ++w) {
            s += psum_s[p * 256 +       row * 4 + w];
            q += psum_s[p * 256 + 128 + row * 4 + w];
        }
        float mu = s * (1.0f / HID);
        float var = q * (1.0f / HID) - mu * mu;
        mu_s[p * 32 + row] = mu;
        rs_s[p * 32 + row] = rsqrtf(var + LN_EPS);
    }
    __syncthreads();

    // ---- P4: normalize both paths in-register; E -> A2 frags, V -> vw partials
    {
        float gE0 = ge1[ncol0], gE1 = ge1[ncol1];
        float tE0 = bte1[ncol0], tE1 = bte1[ncol1];
        float gV0 = gv1[ncol0], gV1 = gv1[ncol1];
        float tV0 = btv1[ncol0], tV1 = btv1[ncol1];
        float w20 = Wv2[ncol0], w21 = Wv2[ncol1];
        // A2 fragment base offsets for the two k-columns this lane produces
        int ks0 = ncol0 >> 5, kq0 = (ncol0 & 31) >> 3, j0 = ncol0 & 7;
        int ks1 = ncol1 >> 5, kq1 = (ncol1 & 31) >> 3, j1 = ncol1 & 7;
        int fo0 = (ks0 * 128 + kq0 * 16) * 8 + j0;
        int fo1 = (ks1 * 128 + kq1 * 16) * 8 + j1;
        #pragma unroll
        for (int mt = 0; mt < 2; ++mt)
            #pragma unroll
            for (int r = 0; r < 4; ++r) {
                int rlow = quad * 4 + r, row = mt * 16 + rlow;
                float mu = mu_s[row], rsv = rs_s[row];
                float muV = mu_s[32 + row], rsV = rs_s[32 + row];
                float h0 = sp((accE[mt][0][r] - mu) * rsv * gE0 + tE0);
                float h1 = sp((accE[mt][1][r] - mu) * rsv * gE1 + tE1);
                frag_s[fo0 + (mt * 64 + rlow) * 8] = (short)f2bf(h0);
                frag_s[fo1 + (mt * 64 + rlow) * 8] = (short)f2bf(h1);
                float v0 = sp((accV[mt][0][r] - muV) * rsV * gV0 + tV0);
                float v1 = sp((accV[mt][1][r] - muV) * rsV * gV1 + tV1);
                float vp = v0 * w20 + v1 * w21;
                #pragma unroll
                for (int m = 1; m < 16; m <<= 1) vp += __shfl_xor(vp, m, 16);
                if (lr == 0) psum_s[row * 4 + wid] = vp;
            }
    }
    __syncthreads();
    if (tid < TE) {
        float s = 0.f;
        #pragma unroll
        for (int w = 0; w < 4; ++w) s += psum_s[tid * 4 + w];
        vw_s[tid] = s + bv2[0];
    }

    // ---- P5: GEMM2 (M=32, N=128, K=128) + softplus -> A3 fragments
    {
        f32x4 acc2[2][2];
        #pragma unroll
        for (int mt = 0; mt < 2; ++mt)
            #pragma unroll
            for (int nt = 0; nt < 2; ++nt) acc2[mt][nt] = zero4;
        for (int ks = 0; ks < 4; ++ks) {
            bf16x8 af0 = *(const bf16x8*)&frag_s[fragOff(ks, 0, lane)];
            bf16x8 af1 = *(const bf16x8*)&frag_s[fragOff(ks, 1, lane)];
            int krow = ks * 32 + quad * 8;
            #pragma unroll
            for (int nt = 0; nt < 2; ++nt) {
                int n = n0w + nt * 16 + lr;
                bf16x8 bw = *(const bf16x8*)&We2T[n * KP2 + krow];
                acc2[0][nt] = __builtin_amdgcn_mfma_f32_16x16x32_bf16(af0, bw, acc2[0][nt], 0, 0, 0);
                acc2[1][nt] = __builtin_amdgcn_mfma_f32_16x16x32_bf16(af1, bw, acc2[1][nt], 0, 0, 0);
            }
        }
        __syncthreads();   // all A2 reads done before overwriting with A3
        #pragma unroll
        for (int nt = 0; nt < 2; ++nt) {
            int kg = n0w + nt * 16 + lr;
            float b2 = be2[kg];
            int ks = kg >> 5, kq = (kg & 31) >> 3, j = kg & 7;
            #pragma unroll
            for (int mt = 0; mt < 2; ++mt)
                #pragma unroll
                for (int r = 0; r < 4; ++r) {
                    short v = (short)f2bf(sp(acc2[mt][nt][r] + b2));
                    frag_s[fragOff(ks, mt, kq * 16 + quad * 4 + r) + j] = v;
                }
        }
    }
    __syncthreads();

    // ---- P6: GEMM3 (M=32, N=128, K=128) + bias + atomic scatter
    {
        f32x4 acc3[2][2];
        #pragma unroll
        for (int mt = 0; mt < 2; ++mt)
            #pragma unroll
            for (int nt = 0; nt < 2; ++nt) acc3[mt][nt] = zero4;
        for (int ks = 0; ks < 4; ++ks) {
            bf16x8 af0 = *(const bf16x8*)&frag_s[fragOff(ks, 0, lane)];
            bf16x8 af1 = *(const bf16x8*)&frag_s[fragOff(ks, 1, lane)];
            int krow = ks * 32 + quad * 8;
            #pragma unroll
            for (int nt = 0; nt < 2; ++nt) {
                int n = n0w + nt * 16 + lr;
                bf16x8 bw = *(const bf16x8*)&We3T[n * KP2 + krow];
                acc3[0][nt] = __builtin_amdgcn_mfma_f32_16x16x32_bf16(af0, bw, acc3[0][nt], 0, 0, 0);
                acc3[1][nt] = __builtin_amdgcn_mfma_f32_16x16x32_bf16(af1, bw, acc3[1][nt], 0, 0, 0);
            }
        }
        #pragma unroll
        for (int nt = 0; nt < 2; ++nt) {
            int n = n0w + nt * 16 + lr;
            float b3 = be3[n];
            #pragma unroll
            for (int mt = 0; mt < 2; ++mt)
                #pragma unroll
                for (int r = 0; r < 4; ++r) {
                    int m = mt * 16 + quad * 4 + r;
                    atomAddF(&mh[(size_t)dst_s[m] * HID + n], acc3[mt][nt][r] + b3);
                }
        }
    }
    // ---- P7: m_v / cnt atomics
    if (tid < TE) {
        int d = dst_s[tid];
        float w = vw_s[tid];
        atomAddF(&mv[2 * d],     w * rel_s[2 * tid]);
        atomAddF(&mv[2 * d + 1], w * rel_s[2 * tid + 1]);
        atomAddF(&cnt[d], 1.0f);
    }
}

// ---------------------------------------------------------------- node kernel
__global__ __launch_bounds__(256)
void eg_node(const float* __restrict__ x,
             const float* __restrict__ Wh1, const float* __restrict__ bh1,
             const float* __restrict__ gh1, const float* __restrict__ bth1,
             const float* __restrict__ Wh2, const float* __restrict__ bh2,
             const float* __restrict__ mh, const float* __restrict__ mv,
             const float* __restrict__ cnt, float* __restrict__ out)
{
    __shared__ float hin_s[PHIN * NST];
    __shared__ float H_s[HID * NST];
    __shared__ float den_s[TN], mu_s[TN], rs_s[TN];

    const int tid = threadIdx.x;
    const int n_base = blockIdx.x * TN;

    if (tid < TN) {
        int n = n_base + tid;
        float den = 1.f, norm = 0.f;
        if (n < NNODE) {
            den = fmaxf(cnt[n], 1.0f);
            float ax = mv[2 * n] / den + 1e-8f;
            float ay = mv[2 * n + 1] / den + 1e-8f;
            norm = sqrtf(ax * ax + ay * ay);
        }
        den_s[tid] = den;
        hin_s[192 * NST + tid] = norm;
    }
    __syncthreads();
    {
        const int c = tid & 63, ng = tid >> 6;
        #pragma unroll
        for (int it = 0; it < 8; ++it) {
            int nl = it * 4 + ng;
            int n = n_base + nl;
            hin_s[c * NST + nl] = (n < NNODE) ? x[(size_t)n * NCH + c] : 0.f;
        }
        const int k = tid & 127, ng2 = tid >> 7;
        #pragma unroll
        for (int it = 0; it < 16; ++it) {
            int nl = it * 2 + ng2;
            int n = n_base + nl;
            hin_s[(NCH + k) * NST + nl] =
                (n < NNODE) ? mh[(size_t)n * HID + k] / den_s[nl] : 0.f;
        }
    }
    __syncthreads();

    const int n0 = (tid & 7) * 4;
    const int j0 = (tid >> 3) * 4;

    {
        float acc[4][4] = {};
        for (int k = 0; k < PHIN; ++k) {
            const float4 a = *(const float4*)&hin_s[k * NST + n0];
            const float4 wb = *(const float4*)(Wh1 + (size_t)k * HID + j0);
            const float w[4] = { wb.x, wb.y, wb.z, wb.w };
            const float aa[4] = { a.x, a.y, a.z, a.w };
            #pragma unroll
            for (int i = 0; i < 4; ++i)
                #pragma unroll
                for (int j = 0; j < 4; ++j) acc[i][j] += aa[i] * w[j];
        }
        #pragma unroll
        for (int j = 0; j < 4; ++j) {
            float b = bh1[j0 + j];
            #pragma unroll
            for (int i = 0; i < 4; ++i)
                H_s[(j0 + j) * NST + n0 + i] = acc[i][j] + b;
        }
    }
    __syncthreads();

    if (tid < TN) {
        float sum = 0.f, sq = 0.f;
        for (int k = 0; k < HID; ++k) {
            float v = H_s[k * NST + tid];
            sum += v; sq += v * v;
        }
        float mu = sum * (1.0f / HID);
        float var = sq * (1.0f / HID) - mu * mu;
        mu_s[tid] = mu;
        rs_s[tid] = rsqrtf(var + LN_EPS);
    }
    __syncthreads();
    {
        const int nl = tid & 31;
        const int jb = (tid >> 5) * 16;
        const float mu = mu_s[nl], rs = rs_s[nl];
        for (int jj = 0; jj < 16; ++jj) {
            int j = jb + jj;
            float v = H_s[j * NST + nl];
            v = (v - mu) * rs * gh1[j] + bth1[j];
            H_s[j * NST + nl] = sp(v);
        }
    }
    __syncthreads();

    {
        const int o0 = (tid >> 3) * 2;
        float acc[4][2] = {};
        for (int k = 0; k < HID; ++k) {
            const float4 a = *(const float4*)&H_s[k * NST + n0];
            const float2 wb = *(const float2*)(Wh2 + (size_t)k * OUTC + o0);
            const float aa[4] = { a.x, a.y, a.z, a.w };
            #pragma unroll
            for (int i = 0; i < 4; ++i) {
                acc[i][0] += aa[i] * wb.x;
                acc[i][1] += aa[i] * wb.y;
            }
        }
        #pragma unroll
        for (int jo = 0; jo < 2; ++jo) {
            float bo = bh2[o0 + jo];
            #pragma unroll
            for (int i = 0; i < 4; ++i) {
                int n = n_base + n0 + i;
                if (n < NNODE) {
                    out[(size_t)n * OUTC + o0 + jo] =
                        x[(size_t)n * NCH + o0 + jo] + acc[i][jo] + bo;
                }
            }
        }
    }
}

// ---------------------------------------------------------------- launch
extern "C" void kernel_launch(void* const* d_in, const int* in_sizes, int n_in,
                              void* d_out, int out_size, void* d_ws, size_t ws_size,
                              hipStream_t stream)
{
    const float* x    = (const float*)d_in[0];
    const float* pos  = (const float*)d_in[1];
    const float* vel  = (const float*)d_in[2];
    const float* We1  = (const float*)d_in[3];
    const float* be1  = (const float*)d_in[4];
    const float* ge1  = (const float*)d_in[5];
    const float* bte1 = (const float*)d_in[6];
    const float* We2  = (const float*)d_in[7];
    const float* be2  = (const float*)d_in[8];
    const float* We3  = (const float*)d_in[9];
    const float* be3  = (const float*)d_in[10];
    const float* Wv1  = (const float*)d_in[11];
    const float* bv1  = (const float*)d_in[12];
    const float* gv1  = (const float*)d_in[13];
    const float* btv1 = (const float*)d_in[14];
    const float* Wv2  = (const float*)d_in[15];
    const float* bv2  = (const float*)d_in[16];
    const float* Wh1  = (const float*)d_in[17];
    const float* bh1  = (const float*)d_in[18];
    const float* gh1  = (const float*)d_in[19];
    const float* bth1 = (const float*)d_in[20];
    const float* Wh2  = (const float*)d_in[21];
    const float* bh2  = (const float*)d_in[22];
    const int*   ei   = (const int*)d_in[23];

    float* mh  = (float*)d_ws;
    float* mv  = mh + (size_t)NNODE * HID;
    float* cnt = mv + (size_t)NNODE * 2;
    short* wt  = (short*)(((float*)d_ws) + WS_WFLOAT);

    size_t zbytes = (size_t)WS_WFLOAT * sizeof(float);
    hipMemsetAsync(d_ws, 0, zbytes, stream);

    eg_prep<<<dim3((WT_TOTAL + 255) / 256), dim3(256), 0, stream>>>(We1, Wv1, We2, We3, wt);

    eg_edge<<<dim3(NEDGE / TE), dim3(256), 0, stream>>>(
        x, pos, vel, be1, ge1, bte1, be2, be3,
        bv1, gv1, btv1, Wv2, bv2, wt, ei, mh, mv, cnt);

    eg_node<<<dim3((NNODE + TN - 1) / TN), dim3(256), 0, stream>>>(
        x, Wh1, bh1, gh1, bth1, Wh2, bh2, mh, mv, cnt, (float*)d_out);
}

// Round 6
// 598.477 us; speedup vs baseline: 4.3043x; 1.0332x over previous
//
#include <hip/hip_runtime.h>
#include <stdint.h>

#define NCH    64
#define HID    128
#define OUTC   64
#define NNODE  20000
#define NEDGE  640000
#define FDIM   133
#define PHIN   193
#define TE     32
#define TN     32
#define NST    36
#define LN_EPS 1e-5f
#define KP1    160          // K of GEMM1, padded (133 -> 160 = 5*32)
#define KP2    128          // K of GEMM2/3
#define CAG    132          // Cagg LDS row stride (128 + 4 pad -> 2-way banks, free)

typedef __attribute__((ext_vector_type(8))) short bf16x8;
typedef __attribute__((ext_vector_type(4))) float f32x4;

__device__ __forceinline__ unsigned short f2bf(float f) {
    union { float f; unsigned int i; } v; v.f = f;
    unsigned int b = v.i;
    return (unsigned short)((b + 0x7FFFu + ((b >> 16) & 1u)) >> 16);
}
// fast softplus: hardware v_exp_f32 / v_log_f32
__device__ __forceinline__ float sp(float xv) {
    return fmaxf(xv, 0.f) + __logf(1.0f + __expf(-fabsf(xv)));
}
__device__ __forceinline__ void atomAddF(float* p, float v) {
    __hip_atomic_fetch_add(p, v, __ATOMIC_RELAXED, __HIP_MEMORY_SCOPE_AGENT);
}
// A/B fragment offset in a [kstep][mtile(2)][lane(64)][8] bf16 buffer
__device__ __forceinline__ int fragOff(int ks, int mt, int lanepos) {
    return ((ks * 2 + mt) * 64 + lanepos) * 8;
}

#define WT_WE1 0
#define WT_WV1 (128 * KP1)
#define WT_WE2 (2 * 128 * KP1)
#define WT_WE3 (2 * 128 * KP1 + 128 * KP2)
#define WT_TOTAL (2 * 128 * KP1 + 2 * 128 * KP2)      // 73728 shorts

// ------------------------------------------------- weight transpose/convert
__global__ __launch_bounds__(256)
void eg_prep(const float* __restrict__ We1, const float* __restrict__ Wv1,
             const float* __restrict__ We2, const float* __restrict__ We3,
             short* __restrict__ wt)
{
    int idx = blockIdx.x * 256 + threadIdx.x;
    if (idx >= WT_TOTAL) return;
    if (idx < WT_WV1) {
        int n = idx / KP1, k = idx % KP1;
        wt[idx] = (k < FDIM) ? (short)f2bf(We1[(size_t)k * HID + n]) : (short)0;
    } else if (idx < WT_WE2) {
        int r = idx - WT_WV1; int n = r / KP1, k = r % KP1;
        wt[idx] = (k < FDIM) ? (short)f2bf(Wv1[(size_t)k * HID + n]) : (short)0;
    } else if (idx < WT_WE3) {
        int r = idx - WT_WE2; int n = r / KP2, k = r % KP2;
        wt[idx] = (short)f2bf(We2[(size_t)k * HID + n]);
    } else {
        int r = idx - WT_WE3; int n = r / KP2, k = r % KP2;
        wt[idx] = (short)f2bf(We3[(size_t)k * HID + n]);
    }
}

// ------------------------------------------------- degree histogram
__global__ __launch_bounds__(256)
void eg_hist(const int* __restrict__ ei, int* __restrict__ deg)
{
    int i = blockIdx.x * 256 + threadIdx.x;
    if (i < NEDGE)
        __hip_atomic_fetch_add(&deg[ei[NEDGE + i]], 1, __ATOMIC_RELAXED, __HIP_MEMORY_SCOPE_AGENT);
}

// ------------------------------------------------- exclusive scan -> cursor
__global__ __launch_bounds__(1024)
void eg_scan(const int* __restrict__ deg, int* __restrict__ cur)
{
    __shared__ int part[1024];
    const int tid = threadIdx.x;
    const int chunk = (NNODE + 1023) / 1024;   // 20
    const int base = tid * chunk;
    const int lim = min(base + chunk, NNODE);
    int s = 0;
    for (int j = base; j < lim; ++j) s += deg[j];
    part[tid] = s;
    __syncthreads();
    for (int off = 1; off < 1024; off <<= 1) {
        int v = (tid >= off) ? part[tid - off] : 0;
        __syncthreads();
        part[tid] += v;
        __syncthreads();
    }
    int run = (tid > 0) ? part[tid - 1] : 0;
    for (int j = base; j < lim; ++j) { cur[j] = run; run += deg[j]; }
}

// ------------------------------------------------- dst-sorted permutation
__global__ __launch_bounds__(256)
void eg_scatter(const int* __restrict__ ei, int* __restrict__ cur,
                int* __restrict__ perm)
{
    int i = blockIdx.x * 256 + threadIdx.x;
    if (i < NEDGE) {
        int d = ei[NEDGE + i];
        int p = __hip_atomic_fetch_add(&cur[d], 1, __ATOMIC_RELAXED, __HIP_MEMORY_SCOPE_AGENT);
        perm[p] = i;
    }
}

// ---------------------------------------------------------------- edge kernel
__global__ __launch_bounds__(256, 5)
void eg_edge(const float* __restrict__ x, const float* __restrict__ pos,
             const float* __restrict__ vel,
             const float* __restrict__ be1, const float* __restrict__ ge1,
             const float* __restrict__ bte1, const float* __restrict__ be2,
             const float* __restrict__ be3,
             const float* __restrict__ bv1, const float* __restrict__ gv1,
             const float* __restrict__ btv1,
             const float* __restrict__ Wv2, const float* __restrict__ bv2,
             const short* __restrict__ wt,
             const int* __restrict__ ei, const int* __restrict__ perm,
             float* __restrict__ mh, float* __restrict__ mv)
{
    __shared__ __align__(16) short frag_s[5 * 2 * 64 * 8];   // 10240 B
    __shared__ __align__(16) float cagg_s[TE * CAG];          // 16896 B
    __shared__ float psum_s[512];                             // 2048 B
    __shared__ float mu_s[64], rs_s[64];
    __shared__ int   dst_s[TE], src_s[TE];
    __shared__ float rel_s[TE * 2], vw_s[TE];

    const int tid  = threadIdx.x;
    const int lane = tid & 63;
    const int wid  = tid >> 6;
    const int lr   = lane & 15;
    const int quad = lane >> 4;
    const int n0w  = wid * 32;
    const int e_base = blockIdx.x * TE;

    const short* We1T = wt + WT_WE1;
    const short* Wv1T = wt + WT_WV1;
    const short* We2T = wt + WT_WE2;
    const short* We3T = wt + WT_WE3;

    // ---- P0: permuted indices + geometry (regs), zero kstep-4 frag region
    float geo[5];
    if (tid < TE) {
        int gi = perm[e_base + tid];            // dst-sorted edge id
        int eS = ei[gi];
        int eD = ei[NEDGE + gi];
        src_s[tid] = eS; dst_s[tid] = eD;
        float rx = pos[2 * eS]     - pos[2 * eD];
        float ry = pos[2 * eS + 1] - pos[2 * eD + 1];
        float vx = vel[2 * eS]     - vel[2 * eD];
        float vy = vel[2 * eS + 1] - vel[2 * eD + 1];
        float dsq = rx * rx + ry * ry;
        float dvr = vx * rx + vy * ry;
        float r2  = fminf(1.0f / (dsq + 0.05f), 20.0f);
        float r6  = fminf(r2 * r2 * r2, 400.0f);
        float r12 = fminf(r6 * r6, 160000.0f);
        geo[0] = dsq; geo[1] = dvr; geo[2] = r2; geo[3] = r6; geo[4] = r12;
        rel_s[2 * tid] = rx; rel_s[2 * tid + 1] = ry;
    }
    if (tid < 128) {   // zero kstep 4 region
        int4 z = {0, 0, 0, 0};
        *(int4*)&frag_s[4 * 2 * 64 * 8 + tid * 8] = z;
    }
    __syncthreads();

    // ---- P1: geo shorts + gather x into A1 fragments (bf16)
    if (tid < TE) {
        int off = fragOff(4, tid >> 4, (tid & 15));
        #pragma unroll
        for (int j = 0; j < 5; ++j) frag_s[off + j] = (short)f2bf(geo[j]);
    }
    {
        const int e = tid & 31, slot = tid >> 5;
        const int d = dst_s[e], s = src_s[e];
        #pragma unroll
        for (int h = 0; h < 2; ++h) {
            int o = slot + h * 8;
            int node = h ? s : d;
            int c0 = (o & 7) * 8;
            const float4 a0 = *(const float4*)&x[(size_t)node * NCH + c0];
            const float4 a1 = *(const float4*)&x[(size_t)node * NCH + c0 + 4];
            bf16x8 v;
            v[0] = (short)f2bf(a0.x); v[1] = (short)f2bf(a0.y);
            v[2] = (short)f2bf(a0.z); v[3] = (short)f2bf(a0.w);
            v[4] = (short)f2bf(a1.x); v[5] = (short)f2bf(a1.y);
            v[6] = (short)f2bf(a1.z); v[7] = (short)f2bf(a1.w);
            int ks = o >> 2, kq = o & 3;
            *(bf16x8*)&frag_s[fragOff(ks, e >> 4, kq * 16 + (e & 15))] = v;
        }
    }
    __syncthreads();

    const int ncol0 = n0w + lr;          // nt=0 column
    const int ncol1 = n0w + 16 + lr;     // nt=1 column

    // ---- P2: dual GEMM1 via MFMA (M=32, N=128, K=160)
    f32x4 zero4 = {0.f, 0.f, 0.f, 0.f};
    f32x4 accE[2][2], accV[2][2];
    #pragma unroll
    for (int mt = 0; mt < 2; ++mt)
        #pragma unroll
        for (int nt = 0; nt < 2; ++nt) { accE[mt][nt] = zero4; accV[mt][nt] = zero4; }
    for (int ks = 0; ks < 5; ++ks) {
        bf16x8 af0 = *(const bf16x8*)&frag_s[fragOff(ks, 0, lane)];
        bf16x8 af1 = *(const bf16x8*)&frag_s[fragOff(ks, 1, lane)];
        int krow = ks * 32 + quad * 8;
        #pragma unroll
        for (int nt = 0; nt < 2; ++nt) {
            int n = n0w + nt * 16 + lr;
            bf16x8 bwE = *(const bf16x8*)&We1T[n * KP1 + krow];
            bf16x8 bwV = *(const bf16x8*)&Wv1T[n * KP1 + krow];
            accE[0][nt] = __builtin_amdgcn_mfma_f32_16x16x32_bf16(af0, bwE, accE[0][nt], 0, 0, 0);
            accE[1][nt] = __builtin_amdgcn_mfma_f32_16x16x32_bf16(af1, bwE, accE[1][nt], 0, 0, 0);
            accV[0][nt] = __builtin_amdgcn_mfma_f32_16x16x32_bf16(af0, bwV, accV[0][nt], 0, 0, 0);
            accV[1][nt] = __builtin_amdgcn_mfma_f32_16x16x32_bf16(af1, bwV, accV[1][nt], 0, 0, 0);
        }
    }
    {
        float be0 = be1[ncol0], be_1 = be1[ncol1];
        float bv0 = bv1[ncol0], bv_1 = bv1[ncol1];
        #pragma unroll
        for (int mt = 0; mt < 2; ++mt)
            #pragma unroll
            for (int r = 0; r < 4; ++r) {
                accE[mt][0][r] += be0; accE[mt][1][r] += be_1;
                accV[mt][0][r] += bv0; accV[mt][1][r] += bv_1;
            }
    }

    // ---- P3: LN stats in-register (16-lane butterflies over lr)
    #pragma unroll
    for (int mt = 0; mt < 2; ++mt)
        #pragma unroll
        for (int r = 0; r < 4; ++r) {
            float se = accE[mt][0][r] + accE[mt][1][r];
            float qe = accE[mt][0][r] * accE[mt][0][r] + accE[mt][1][r] * accE[mt][1][r];
            float sv = accV[mt][0][r] + accV[mt][1][r];
            float qv = accV[mt][0][r] * accV[mt][0][r] + accV[mt][1][r] * accV[mt][1][r];
            #pragma unroll
            for (int m = 1; m < 16; m <<= 1) {
                se += __shfl_xor(se, m, 16);
                qe += __shfl_xor(qe, m, 16);
                sv += __shfl_xor(sv, m, 16);
                qv += __shfl_xor(qv, m, 16);
            }
            if (lr == 0) {
                int row = mt * 16 + quad * 4 + r;
                psum_s[      row * 4 + wid] = se;
                psum_s[128 + row * 4 + wid] = qe;
                psum_s[256 + row * 4 + wid] = sv;
                psum_s[384 + row * 4 + wid] = qv;
            }
        }
    __syncthreads();
    if (tid < 64) {
        int p = tid >> 5, row = tid & 31;
        float s = 0.f, q = 0.f;
        #pragma unroll
        for (int w = 0; w < 4; ++w) {
            s += psum_s[p * 256 +       row * 4 + w];
            q += psum_s[p * 256 + 128 + row * 4 + w];
        }
        float mu = s * (1.0f / HID);
        float var = q * (1.0f / HID) - mu * mu;
        mu_s[p * 32 + row] = mu;
        rs_s[p * 32 + row] = rsqrtf(var + LN_EPS);
    }
    __syncthreads();

    // ---- P4: normalize in-register; E -> A2 frags, V -> vw partials
    {
        float gE0 = ge1[ncol0], gE1 = ge1[ncol1];
        float tE0 = bte1[ncol0], tE1 = bte1[ncol1];
        float gV0 = gv1[ncol0], gV1 = gv1[ncol1];
        float tV0 = btv1[ncol0], tV1 = btv1[ncol1];
        float w20 = Wv2[ncol0], w21 = Wv2[ncol1];
        int ks0 = ncol0 >> 5, kq0 = (ncol0 & 31) >> 3, j0 = ncol0 & 7;
        int ks1 = ncol1 >> 5, kq1 = (ncol1 & 31) >> 3, j1 = ncol1 & 7;
        int fo0 = (ks0 * 128 + kq0 * 16) * 8 + j0;
        int fo1 = (ks1 * 128 + kq1 * 16) * 8 + j1;
        #pragma unroll
        for (int mt = 0; mt < 2; ++mt)
            #pragma unroll
            for (int r = 0; r < 4; ++r) {
                int rlow = quad * 4 + r, row = mt * 16 + rlow;
                float mu = mu_s[row], rsv = rs_s[row];
                float muV = mu_s[32 + row], rsV = rs_s[32 + row];
                float h0 = sp((accE[mt][0][r] - mu) * rsv * gE0 + tE0);
                float h1 = sp((accE[mt][1][r] - mu) * rsv * gE1 + tE1);
                frag_s[fo0 + (mt * 64 + rlow) * 8] = (short)f2bf(h0);
                frag_s[fo1 + (mt * 64 + rlow) * 8] = (short)f2bf(h1);
                float v0 = sp((accV[mt][0][r] - muV) * rsV * gV0 + tV0);
                float v1 = sp((accV[mt][1][r] - muV) * rsV * gV1 + tV1);
                float vp = v0 * w20 + v1 * w21;
                #pragma unroll
                for (int m = 1; m < 16; m <<= 1) vp += __shfl_xor(vp, m, 16);
                if (lr == 0) psum_s[row * 4 + wid] = vp;
            }
    }
    __syncthreads();
    if (tid < TE) {
        float s = 0.f;
        #pragma unroll
        for (int w = 0; w < 4; ++w) s += psum_s[tid * 4 + w];
        vw_s[tid] = s + bv2[0];
    }

    // ---- P5: GEMM2 (M=32, N=128, K=128) + softplus -> A3 fragments
    {
        f32x4 acc2[2][2];
        #pragma unroll
        for (int mt = 0; mt < 2; ++mt)
            #pragma unroll
            for (int nt = 0; nt < 2; ++nt) acc2[mt][nt] = zero4;
        for (int ks = 0; ks < 4; ++ks) {
            bf16x8 af0 = *(const bf16x8*)&frag_s[fragOff(ks, 0, lane)];
            bf16x8 af1 = *(const bf16x8*)&frag_s[fragOff(ks, 1, lane)];
            int krow = ks * 32 + quad * 8;
            #pragma unroll
            for (int nt = 0; nt < 2; ++nt) {
                int n = n0w + nt * 16 + lr;
                bf16x8 bw = *(const bf16x8*)&We2T[n * KP2 + krow];
                acc2[0][nt] = __builtin_amdgcn_mfma_f32_16x16x32_bf16(af0, bw, acc2[0][nt], 0, 0, 0);
                acc2[1][nt] = __builtin_amdgcn_mfma_f32_16x16x32_bf16(af1, bw, acc2[1][nt], 0, 0, 0);
            }
        }
        __syncthreads();   // all A2 reads done before overwriting with A3
        #pragma unroll
        for (int nt = 0; nt < 2; ++nt) {
            int kg = n0w + nt * 16 + lr;
            float b2 = be2[kg];
            int ks = kg >> 5, kq = (kg & 31) >> 3, j = kg & 7;
            #pragma unroll
            for (int mt = 0; mt < 2; ++mt)
                #pragma unroll
                for (int r = 0; r < 4; ++r) {
                    short v = (short)f2bf(sp(acc2[mt][nt][r] + b2));
                    frag_s[fragOff(ks, mt, kq * 16 + quad * 4 + r) + j] = v;
                }
        }
    }
    __syncthreads();

    // ---- P6: GEMM3 (M=32, N=128, K=128) + bias -> Cagg LDS
    {
        f32x4 acc3[2][2];
        #pragma unroll
        for (int mt = 0; mt < 2; ++mt)
            #pragma unroll
            for (int nt = 0; nt < 2; ++nt) acc3[mt][nt] = zero4;
        for (int ks = 0; ks < 4; ++ks) {
            bf16x8 af0 = *(const bf16x8*)&frag_s[fragOff(ks, 0, lane)];
            bf16x8 af1 = *(const bf16x8*)&frag_s[fragOff(ks, 1, lane)];
            int krow = ks * 32 + quad * 8;
            #pragma unroll
            for (int nt = 0; nt < 2; ++nt) {
                int n = n0w + nt * 16 + lr;
                bf16x8 bw = *(const bf16x8*)&We3T[n * KP2 + krow];
                acc3[0][nt] = __builtin_amdgcn_mfma_f32_16x16x32_bf16(af0, bw, acc3[0][nt], 0, 0, 0);
                acc3[1][nt] = __builtin_amdgcn_mfma_f32_16x16x32_bf16(af1, bw, acc3[1][nt], 0, 0, 0);
            }
        }
        #pragma unroll
        for (int nt = 0; nt < 2; ++nt) {
            int n = n0w + nt * 16 + lr;
            float b3 = be3[n];
            #pragma unroll
            for (int mt = 0; mt < 2; ++mt)
                #pragma unroll
                for (int r = 0; r < 4; ++r) {
                    int m = mt * 16 + quad * 4 + r;
                    cagg_s[m * CAG + n] = acc3[mt][nt][r] + b3;
                }
        }
    }
    __syncthreads();

    // ---- P7: dst-run segmented atomic flush (rows sorted by dst)
    {
        const int c = tid & 127, h = tid >> 7;
        const int m0 = h * 16;
        float run = cagg_s[m0 * CAG + c];
        int curd = dst_s[m0];
        #pragma unroll
        for (int m = m0 + 1; m < m0 + 16; ++m) {
            int d = dst_s[m];                  // LDS broadcast, wave-uniform branch
            float v = cagg_s[m * CAG + c];
            if (d == curd) run += v;
            else { atomAddF(&mh[(size_t)curd * HID + c], run); curd = d; run = v; }
        }
        atomAddF(&mh[(size_t)curd * HID + c], run);
    }
    // ---- P8: m_v segmented flush (cnt comes from the degree histogram)
    if (tid < 2) {
        const int c = tid;
        float run = vw_s[0] * rel_s[c];
        int curd = dst_s[0];
        for (int m = 1; m < TE; ++m) {
            int d = dst_s[m];
            float v = vw_s[m] * rel_s[2 * m + c];
            if (d == curd) run += v;
            else { atomAddF(&mv[2 * curd + c], run); curd = d; run = v; }
        }
        atomAddF(&mv[2 * curd + c], run);
    }
}

// ---------------------------------------------------------------- node kernel
__global__ __launch_bounds__(256)
void eg_node(const float* __restrict__ x,
             const float* __restrict__ Wh1, const float* __restrict__ bh1,
             const float* __restrict__ gh1, const float* __restrict__ bth1,
             const float* __restrict__ Wh2, const float* __restrict__ bh2,
             const float* __restrict__ mh, const float* __restrict__ mv,
             const int* __restrict__ deg, float* __restrict__ out)
{
    __shared__ float hin_s[PHIN * NST];
    __shared__ float H_s[HID * NST];
    __shared__ float den_s[TN], mu_s[TN], rs_s[TN];

    const int tid = threadIdx.x;
    const int n_base = blockIdx.x * TN;

    if (tid < TN) {
        int n = n_base + tid;
        float den = 1.f, norm = 0.f;
        if (n < NNODE) {
            den = fmaxf((float)deg[n], 1.0f);
            float ax = mv[2 * n] / den + 1e-8f;
            float ay = mv[2 * n + 1] / den + 1e-8f;
            norm = sqrtf(ax * ax + ay * ay);
        }
        den_s[tid] = den;
        hin_s[192 * NST + tid] = norm;
    }
    __syncthreads();
    {
        const int c = tid & 63, ng = tid >> 6;
        #pragma unroll
        for (int it = 0; it < 8; ++it) {
            int nl = it * 4 + ng;
            int n = n_base + nl;
            hin_s[c * NST + nl] = (n < NNODE) ? x[(size_t)n * NCH + c] : 0.f;
        }
        const int k = tid & 127, ng2 = tid >> 7;
        #pragma unroll
        for (int it = 0; it < 16; ++it) {
            int nl = it * 2 + ng2;
            int n = n_base + nl;
            hin_s[(NCH + k) * NST + nl] =
                (n < NNODE) ? mh[(size_t)n * HID + k] / den_s[nl] : 0.f;
        }
    }
    __syncthreads();

    const int n0 = (tid & 7) * 4;
    const int j0 = (tid >> 3) * 4;

    {
        float acc[4][4] = {};
        for (int k = 0; k < PHIN; ++k) {
            const float4 a = *(const float4*)&hin_s[k * NST + n0];
            const float4 wb = *(const float4*)(Wh1 + (size_t)k * HID + j0);
            const float w[4] = { wb.x, wb.y, wb.z, wb.w };
            const float aa[4] = { a.x, a.y, a.z, a.w };
            #pragma unroll
            for (int i = 0; i < 4; ++i)
                #pragma unroll
                for (int j = 0; j < 4; ++j) acc[i][j] += aa[i] * w[j];
        }
        #pragma unroll
        for (int j = 0; j < 4; ++j) {
            float b = bh1[j0 + j];
            #pragma unroll
            for (int i = 0; i < 4; ++i)
                H_s[(j0 + j) * NST + n0 + i] = acc[i][j] + b;
        }
    }
    __syncthreads();

    if (tid < TN) {
        float sum = 0.f, sq = 0.f;
        for (int k = 0; k < HID; ++k) {
            float v = H_s[k * NST + tid];
            sum += v; sq += v * v;
        }
        float mu = sum * (1.0f / HID);
        float var = sq * (1.0f / HID) - mu * mu;
        mu_s[tid] = mu;
        rs_s[tid] = rsqrtf(var + LN_EPS);
    }
    __syncthreads();
    {
        const int nl = tid & 31;
        const int jb = (tid >> 5) * 16;
        const float mu = mu_s[nl], rs = rs_s[nl];
        for (int jj = 0; jj < 16; ++jj) {
            int j = jb + jj;
            float v = H_s[j * NST + nl];
            v = (v - mu) * rs * gh1[j] + bth1[j];
            H_s[j * NST + nl] = sp(v);
        }
    }
    __syncthreads();

    {
        const int o0 = (tid >> 3) * 2;
        float acc[4][2] = {};
        for (int k = 0; k < HID; ++k) {
            const float4 a = *(const float4*)&H_s[k * NST + n0];
            const float2 wb = *(const float2*)(Wh2 + (size_t)k * OUTC + o0);
            const float aa[4] = { a.x, a.y, a.z, a.w };
            #pragma unroll
            for (int i = 0; i < 4; ++i) {
                acc[i][0] += aa[i] * wb.x;
                acc[i][1] += aa[i] * wb.y;
            }
        }
        #pragma unroll
        for (int jo = 0; jo < 2; ++jo) {
            float bo = bh2[o0 + jo];
            #pragma unroll
            for (int i = 0; i < 4; ++i) {
                int n = n_base + n0 + i;
                if (n < NNODE) {
                    out[(size_t)n * OUTC + o0 + jo] =
                        x[(size_t)n * NCH + o0 + jo] + acc[i][jo] + bo;
                }
            }
        }
    }
}

// ---------------------------------------------------------------- launch
extern "C" void kernel_launch(void* const* d_in, const int* in_sizes, int n_in,
                              void* d_out, int out_size, void* d_ws, size_t ws_size,
                              hipStream_t stream)
{
    const float* x    = (const float*)d_in[0];
    const float* pos  = (const float*)d_in[1];
    const float* vel  = (const float*)d_in[2];
    const float* We1  = (const float*)d_in[3];
    const float* be1  = (const float*)d_in[4];
    const float* ge1  = (const float*)d_in[5];
    const float* bte1 = (const float*)d_in[6];
    const float* We2  = (const float*)d_in[7];
    const float* be2  = (const float*)d_in[8];
    const float* We3  = (const float*)d_in[9];
    const float* be3  = (const float*)d_in[10];
    const float* Wv1  = (const float*)d_in[11];
    const float* bv1  = (const float*)d_in[12];
    const float* gv1  = (const float*)d_in[13];
    const float* btv1 = (const float*)d_in[14];
    const float* Wv2  = (const float*)d_in[15];
    const float* bv2  = (const float*)d_in[16];
    const float* Wh1  = (const float*)d_in[17];
    const float* bh1  = (const float*)d_in[18];
    const float* gh1  = (const float*)d_in[19];
    const float* bth1 = (const float*)d_in[20];
    const float* Wh2  = (const float*)d_in[21];
    const float* bh2  = (const float*)d_in[22];
    const int*   ei   = (const int*)d_in[23];

    // workspace layout
    float* mh   = (float*)d_ws;                      // 2,560,000 f
    float* mv   = mh + (size_t)NNODE * HID;          // 40,000 f
    int*   deg  = (int*)(mv + NNODE * 2);            // 20,000 i
    int*   cur  = deg + NNODE;                       // 20,000 i
    int*   perm = cur + NNODE;                       // 640,000 i
    short* wt   = (short*)(perm + NEDGE);            // 73,728 s

    // zero mh, mv, deg in one shot (contiguous)
    size_t zbytes = ((size_t)NNODE * HID + NNODE * 2 + NNODE) * sizeof(float);
    hipMemsetAsync(d_ws, 0, zbytes, stream);

    eg_prep<<<dim3((WT_TOTAL + 255) / 256), dim3(256), 0, stream>>>(We1, Wv1, We2, We3, wt);
    eg_hist<<<dim3(NEDGE / 256), dim3(256), 0, stream>>>(ei, deg);
    eg_scan<<<dim3(1), dim3(1024), 0, stream>>>(deg, cur);
    eg_scatter<<<dim3(NEDGE / 256), dim3(256), 0, stream>>>(ei, cur, perm);

    eg_edge<<<dim3(NEDGE / TE), dim3(256), 0, stream>>>(
        x, pos, vel, be1, ge1, bte1, be2, be3,
        bv1, gv1, btv1, Wv2, bv2, wt, ei, perm, mh, mv);

    eg_node<<<dim3((NNODE + TN - 1) / TN), dim3(256), 0, stream>>>(
        x, Wh1, bh1, gh1, bth1, Wh2, bh2, mh, mv, deg, (float*)d_out);
}

// Round 7
// 542.516 us; speedup vs baseline: 4.7482x; 1.1032x over previous
//
#include <hip/hip_runtime.h>
#include <stdint.h>

#define NCH    64
#define HID    128
#define OUTC   64
#define NNODE  20000
#define NEDGE  640000
#define FDIM   133
#define TE     32
#define TN     32
#define LN_EPS 1e-5f
#define KP1    160          // K of edge GEMM1, padded (133 -> 160 = 5*32)
#define KP2    128          // K of edge GEMM2/3
#define KN1    224          // K of node GEMM1, padded (193 -> 224 = 7*32)
#define CAGS   130          // bf16 Cagg LDS row stride (shorts); 65%32=1 -> de-aliased

typedef __attribute__((ext_vector_type(8))) short bf16x8;
typedef __attribute__((ext_vector_type(4))) float f32x4;

__device__ __forceinline__ unsigned short f2bf(float f) {
    union { float f; unsigned int i; } v; v.f = f;
    unsigned int b = v.i;
    return (unsigned short)((b + 0x7FFFu + ((b >> 16) & 1u)) >> 16);
}
#if defined(__has_builtin)
#if __has_builtin(__builtin_amdgcn_cvt_pk_bf16_f32)
#define HAVE_PK_BF16 1
#endif
#endif
__device__ __forceinline__ unsigned int f2bf_pk(float a, float b) {
#ifdef HAVE_PK_BF16
    auto r = __builtin_amdgcn_cvt_pk_bf16_f32(a, b);
    return __builtin_bit_cast(unsigned int, r);
#else
    return (unsigned int)f2bf(a) | ((unsigned int)f2bf(b) << 16);
#endif
}
__device__ __forceinline__ float bfu2f(unsigned short u) {
    union { unsigned int i; float f; } v; v.i = ((unsigned int)u) << 16; return v.f;
}
// fast softplus: hardware v_exp_f32 / v_log_f32
__device__ __forceinline__ float sp(float xv) {
    return fmaxf(xv, 0.f) + __logf(1.0f + __expf(-fabsf(xv)));
}
__device__ __forceinline__ void atomAddF(float* p, float v) {
    __hip_atomic_fetch_add(p, v, __ATOMIC_RELAXED, __HIP_MEMORY_SCOPE_AGENT);
}
// A/B fragment offset in a [kstep][mtile(2)][lane(64)][8] bf16 buffer
__device__ __forceinline__ int fragOff(int ks, int mt, int lanepos) {
    return ((ks * 2 + mt) * 64 + lanepos) * 8;
}

#define WT_WE1 0
#define WT_WV1 (128 * KP1)
#define WT_WE2 (2 * 128 * KP1)
#define WT_WE3 (2 * 128 * KP1 + 128 * KP2)
#define WT_WH1 (2 * 128 * KP1 + 2 * 128 * KP2)            // 73728
#define WT_WH2 (WT_WH1 + 128 * KN1)                        // +28672
#define WT_TOTAL (WT_WH2 + 64 * KP2)                       // 110592 shorts

// ------------------------------------------------- weight transpose/convert
__global__ __launch_bounds__(256)
void eg_prep(const float* __restrict__ We1, const float* __restrict__ Wv1,
             const float* __restrict__ We2, const float* __restrict__ We3,
             const float* __restrict__ Wh1, const float* __restrict__ Wh2,
             short* __restrict__ wt)
{
    int idx = blockIdx.x * 256 + threadIdx.x;
    if (idx >= WT_TOTAL) return;
    if (idx < WT_WV1) {
        int n = idx / KP1, k = idx % KP1;
        wt[idx] = (k < FDIM) ? (short)f2bf(We1[(size_t)k * HID + n]) : (short)0;
    } else if (idx < WT_WE2) {
        int r = idx - WT_WV1; int n = r / KP1, k = r % KP1;
        wt[idx] = (k < FDIM) ? (short)f2bf(Wv1[(size_t)k * HID + n]) : (short)0;
    } else if (idx < WT_WE3) {
        int r = idx - WT_WE2; int n = r / KP2, k = r % KP2;
        wt[idx] = (short)f2bf(We2[(size_t)k * HID + n]);
    } else if (idx < WT_WH1) {
        int r = idx - WT_WE3; int n = r / KP2, k = r % KP2;
        wt[idx] = (short)f2bf(We3[(size_t)k * HID + n]);
    } else if (idx < WT_WH2) {
        int r = idx - WT_WH1; int n = r / KN1, k = r % KN1;
        wt[idx] = (k < 193) ? (short)f2bf(Wh1[(size_t)k * HID + n]) : (short)0;
    } else {
        int r = idx - WT_WH2; int n = r / KP2, k = r % KP2;
        wt[idx] = (short)f2bf(Wh2[(size_t)k * OUTC + n]);
    }
}

// ------------------------------------------------- degree histogram
__global__ __launch_bounds__(256)
void eg_hist(const int* __restrict__ ei, int* __restrict__ deg)
{
    int i = blockIdx.x * 256 + threadIdx.x;
    if (i < NEDGE)
        __hip_atomic_fetch_add(&deg[ei[NEDGE + i]], 1, __ATOMIC_RELAXED, __HIP_MEMORY_SCOPE_AGENT);
}

// ------------------------------------------------- exclusive scan -> cursor
__global__ __launch_bounds__(1024)
void eg_scan(const int* __restrict__ deg, int* __restrict__ cur)
{
    __shared__ int part[1024];
    const int tid = threadIdx.x;
    const int chunk = (NNODE + 1023) / 1024;   // 20
    const int base = tid * chunk;
    const int lim = min(base + chunk, NNODE);
    int s = 0;
    for (int j = base; j < lim; ++j) s += deg[j];
    part[tid] = s;
    __syncthreads();
    for (int off = 1; off < 1024; off <<= 1) {
        int v = (tid >= off) ? part[tid - off] : 0;
        __syncthreads();
        part[tid] += v;
        __syncthreads();
    }
    int run = (tid > 0) ? part[tid - 1] : 0;
    for (int j = base; j < lim; ++j) { cur[j] = run; run += deg[j]; }
}

// ------------------------------------------------- dst-sorted permutation
__global__ __launch_bounds__(256)
void eg_scatter(const int* __restrict__ ei, int* __restrict__ cur,
                int* __restrict__ perm)
{
    int i = blockIdx.x * 256 + threadIdx.x;
    if (i < NEDGE) {
        int d = ei[NEDGE + i];
        int p = __hip_atomic_fetch_add(&cur[d], 1, __ATOMIC_RELAXED, __HIP_MEMORY_SCOPE_AGENT);
        perm[p] = i;
    }
}

// ---------------------------------------------------------------- edge kernel
__global__ __launch_bounds__(256, 7)
void eg_edge(const float* __restrict__ x, const float* __restrict__ pos,
             const float* __restrict__ vel,
             const float* __restrict__ be1, const float* __restrict__ ge1,
             const float* __restrict__ bte1, const float* __restrict__ be2,
             const float* __restrict__ be3,
             const float* __restrict__ bv1, const float* __restrict__ gv1,
             const float* __restrict__ btv1,
             const float* __restrict__ Wv2, const float* __restrict__ bv2,
             const short* __restrict__ wt,
             const int* __restrict__ ei, const int* __restrict__ perm,
             float* __restrict__ mh, float* __restrict__ mv)
{
    __shared__ __align__(16) short frag_s[5 * 2 * 64 * 8];        // 10240 B
    __shared__ __align__(4) unsigned short cagg_s[TE * CAGS];     // 8320 B
    __shared__ float psum_s[512];                                  // 2048 B
    __shared__ float mu_s[64], rs_s[64];
    __shared__ int   dst_s[TE], src_s[TE];
    __shared__ float rel_s[TE * 2], vw_s[TE];

    const int tid  = threadIdx.x;
    const int lane = tid & 63;
    const int wid  = tid >> 6;
    const int lr   = lane & 15;
    const int quad = lane >> 4;
    const int n0w  = wid * 32;
    const int e_base = blockIdx.x * TE;

    const short* We1T = wt + WT_WE1;
    const short* Wv1T = wt + WT_WV1;
    const short* We2T = wt + WT_WE2;
    const short* We3T = wt + WT_WE3;

    // ---- P0: permuted indices + geometry, zero kstep-4 frag region
    float geo[5];
    if (tid < TE) {
        int gi = perm[e_base + tid];
        int eS = ei[gi];
        int eD = ei[NEDGE + gi];
        src_s[tid] = eS; dst_s[tid] = eD;
        float rx = pos[2 * eS]     - pos[2 * eD];
        float ry = pos[2 * eS + 1] - pos[2 * eD + 1];
        float vx = vel[2 * eS]     - vel[2 * eD];
        float vy = vel[2 * eS + 1] - vel[2 * eD + 1];
        float dsq = rx * rx + ry * ry;
        float dvr = vx * rx + vy * ry;
        float r2  = fminf(1.0f / (dsq + 0.05f), 20.0f);
        float r6  = fminf(r2 * r2 * r2, 400.0f);
        float r12 = fminf(r6 * r6, 160000.0f);
        geo[0] = dsq; geo[1] = dvr; geo[2] = r2; geo[3] = r6; geo[4] = r12;
        rel_s[2 * tid] = rx; rel_s[2 * tid + 1] = ry;
    }
    if (tid < 128) {
        int4 z = {0, 0, 0, 0};
        *(int4*)&frag_s[4 * 2 * 64 * 8 + tid * 8] = z;
    }
    __syncthreads();

    // ---- P1: geo + gather x into A1 fragments (packed bf16)
    if (tid < TE) {
        int off = fragOff(4, tid >> 4, (tid & 15));
        #pragma unroll
        for (int j = 0; j < 5; ++j) frag_s[off + j] = (short)f2bf(geo[j]);
    }
    {
        const int e = tid & 31, slot = tid >> 5;
        const int d = dst_s[e], s = src_s[e];
        #pragma unroll
        for (int h = 0; h < 2; ++h) {
            int o = slot + h * 8;
            int node = h ? s : d;
            int c0 = (o & 7) * 8;
            const float4 a0 = *(const float4*)&x[(size_t)node * NCH + c0];
            const float4 a1 = *(const float4*)&x[(size_t)node * NCH + c0 + 4];
            uint4 pk;
            pk.x = f2bf_pk(a0.x, a0.y); pk.y = f2bf_pk(a0.z, a0.w);
            pk.z = f2bf_pk(a1.x, a1.y); pk.w = f2bf_pk(a1.z, a1.w);
            int ks = o >> 2, kq = o & 3;
            *(uint4*)&frag_s[fragOff(ks, e >> 4, kq * 16 + (e & 15))] = pk;
        }
    }
    __syncthreads();

    const int ncol0 = n0w + lr;
    const int ncol1 = n0w + 16 + lr;

    // ---- P2: dual GEMM1 via MFMA (M=32, N=128, K=160)
    f32x4 zero4 = {0.f, 0.f, 0.f, 0.f};
    f32x4 accE[2][2], accV[2][2];
    #pragma unroll
    for (int mt = 0; mt < 2; ++mt)
        #pragma unroll
        for (int nt = 0; nt < 2; ++nt) { accE[mt][nt] = zero4; accV[mt][nt] = zero4; }
    for (int ks = 0; ks < 5; ++ks) {
        bf16x8 af0 = *(const bf16x8*)&frag_s[fragOff(ks, 0, lane)];
        bf16x8 af1 = *(const bf16x8*)&frag_s[fragOff(ks, 1, lane)];
        int krow = ks * 32 + quad * 8;
        #pragma unroll
        for (int nt = 0; nt < 2; ++nt) {
            int n = n0w + nt * 16 + lr;
            bf16x8 bwE = *(const bf16x8*)&We1T[n * KP1 + krow];
            bf16x8 bwV = *(const bf16x8*)&Wv1T[n * KP1 + krow];
            accE[0][nt] = __builtin_amdgcn_mfma_f32_16x16x32_bf16(af0, bwE, accE[0][nt], 0, 0, 0);
            accE[1][nt] = __builtin_amdgcn_mfma_f32_16x16x32_bf16(af1, bwE, accE[1][nt], 0, 0, 0);
            accV[0][nt] = __builtin_amdgcn_mfma_f32_16x16x32_bf16(af0, bwV, accV[0][nt], 0, 0, 0);
            accV[1][nt] = __builtin_amdgcn_mfma_f32_16x16x32_bf16(af1, bwV, accV[1][nt], 0, 0, 0);
        }
    }
    {
        float be0 = be1[ncol0], be_1 = be1[ncol1];
        float bv0 = bv1[ncol0], bv_1 = bv1[ncol1];
        #pragma unroll
        for (int mt = 0; mt < 2; ++mt)
            #pragma unroll
            for (int r = 0; r < 4; ++r) {
                accE[mt][0][r] += be0; accE[mt][1][r] += be_1;
                accV[mt][0][r] += bv0; accV[mt][1][r] += bv_1;
            }
    }

    // ---- P3: LN stats in-register (16-lane butterflies over lr)
    #pragma unroll
    for (int mt = 0; mt < 2; ++mt)
        #pragma unroll
        for (int r = 0; r < 4; ++r) {
            float se = accE[mt][0][r] + accE[mt][1][r];
            float qe = accE[mt][0][r] * accE[mt][0][r] + accE[mt][1][r] * accE[mt][1][r];
            float sv = accV[mt][0][r] + accV[mt][1][r];
            float qv = accV[mt][0][r] * accV[mt][0][r] + accV[mt][1][r] * accV[mt][1][r];
            #pragma unroll
            for (int m = 1; m < 16; m <<= 1) {
                se += __shfl_xor(se, m, 16);
                qe += __shfl_xor(qe, m, 16);
                sv += __shfl_xor(sv, m, 16);
                qv += __shfl_xor(qv, m, 16);
            }
            if (lr == 0) {
                int row = mt * 16 + quad * 4 + r;
                psum_s[      row * 4 + wid] = se;
                psum_s[128 + row * 4 + wid] = qe;
                psum_s[256 + row * 4 + wid] = sv;
                psum_s[384 + row * 4 + wid] = qv;
            }
        }
    __syncthreads();
    if (tid < 64) {
        int p = tid >> 5, row = tid & 31;
        float s = 0.f, q = 0.f;
        #pragma unroll
        for (int w = 0; w < 4; ++w) {
            s += psum_s[p * 256 +       row * 4 + w];
            q += psum_s[p * 256 + 128 + row * 4 + w];
        }
        float mu = s * (1.0f / HID);
        float var = q * (1.0f / HID) - mu * mu;
        mu_s[p * 32 + row] = mu;
        rs_s[p * 32 + row] = rsqrtf(var + LN_EPS);
    }
    __syncthreads();

    // ---- P4: normalize in-register; E -> A2 frags, V -> vw partials
    {
        float gE0 = ge1[ncol0], gE1 = ge1[ncol1];
        float tE0 = bte1[ncol0], tE1 = bte1[ncol1];
        float gV0 = gv1[ncol0], gV1 = gv1[ncol1];
        float tV0 = btv1[ncol0], tV1 = btv1[ncol1];
        float w20 = Wv2[ncol0], w21 = Wv2[ncol1];
        int ks0 = ncol0 >> 5, kq0 = (ncol0 & 31) >> 3, j0 = ncol0 & 7;
        int ks1 = ncol1 >> 5, kq1 = (ncol1 & 31) >> 3, j1 = ncol1 & 7;
        int fo0 = (ks0 * 128 + kq0 * 16) * 8 + j0;
        int fo1 = (ks1 * 128 + kq1 * 16) * 8 + j1;
        #pragma unroll
        for (int mt = 0; mt < 2; ++mt)
            #pragma unroll
            for (int r = 0; r < 4; ++r) {
                int rlow = quad * 4 + r, row = mt * 16 + rlow;
                float mu = mu_s[row], rsv = rs_s[row];
                float muV = mu_s[32 + row], rsV = rs_s[32 + row];
                float h0 = sp((accE[mt][0][r] - mu) * rsv * gE0 + tE0);
                float h1 = sp((accE[mt][1][r] - mu) * rsv * gE1 + tE1);
                unsigned int ph = f2bf_pk(h0, h1);
                frag_s[fo0 + (mt * 64 + rlow) * 8] = (short)(ph & 0xFFFFu);
                frag_s[fo1 + (mt * 64 + rlow) * 8] = (short)(ph >> 16);
                float v0 = sp((accV[mt][0][r] - muV) * rsV * gV0 + tV0);
                float v1 = sp((accV[mt][1][r] - muV) * rsV * gV1 + tV1);
                float vp = v0 * w20 + v1 * w21;
                #pragma unroll
                for (int m = 1; m < 16; m <<= 1) vp += __shfl_xor(vp, m, 16);
                if (lr == 0) psum_s[row * 4 + wid] = vp;
            }
    }
    __syncthreads();
    if (tid < TE) {
        float s = 0.f;
        #pragma unroll
        for (int w = 0; w < 4; ++w) s += psum_s[tid * 4 + w];
        vw_s[tid] = s + bv2[0];
    }

    // ---- P5: GEMM2 (M=32, N=128, K=128) + softplus -> A3 fragments
    {
        f32x4 acc2[2][2];
        #pragma unroll
        for (int mt = 0; mt < 2; ++mt)
            #pragma unroll
            for (int nt = 0; nt < 2; ++nt) acc2[mt][nt] = zero4;
        for (int ks = 0; ks < 4; ++ks) {
            bf16x8 af0 = *(const bf16x8*)&frag_s[fragOff(ks, 0, lane)];
            bf16x8 af1 = *(const bf16x8*)&frag_s[fragOff(ks, 1, lane)];
            int krow = ks * 32 + quad * 8;
            #pragma unroll
            for (int nt = 0; nt < 2; ++nt) {
                int n = n0w + nt * 16 + lr;
                bf16x8 bw = *(const bf16x8*)&We2T[n * KP2 + krow];
                acc2[0][nt] = __builtin_amdgcn_mfma_f32_16x16x32_bf16(af0, bw, acc2[0][nt], 0, 0, 0);
                acc2[1][nt] = __builtin_amdgcn_mfma_f32_16x16x32_bf16(af1, bw, acc2[1][nt], 0, 0, 0);
            }
        }
        __syncthreads();   // all A2 reads done before overwriting with A3
        #pragma unroll
        for (int nt = 0; nt < 2; ++nt) {
            int kg = n0w + nt * 16 + lr;
            float b2 = be2[kg];
            int ks = kg >> 5, kq = (kg & 31) >> 3, j = kg & 7;
            #pragma unroll
            for (int mt = 0; mt < 2; ++mt) {
                unsigned int u0 = f2bf_pk(sp(acc2[mt][nt][0] + b2), sp(acc2[mt][nt][1] + b2));
                unsigned int u1 = f2bf_pk(sp(acc2[mt][nt][2] + b2), sp(acc2[mt][nt][3] + b2));
                frag_s[fragOff(ks, mt, kq * 16 + quad * 4 + 0) + j] = (short)(u0 & 0xFFFFu);
                frag_s[fragOff(ks, mt, kq * 16 + quad * 4 + 1) + j] = (short)(u0 >> 16);
                frag_s[fragOff(ks, mt, kq * 16 + quad * 4 + 2) + j] = (short)(u1 & 0xFFFFu);
                frag_s[fragOff(ks, mt, kq * 16 + quad * 4 + 3) + j] = (short)(u1 >> 16);
            }
        }
    }
    __syncthreads();

    // ---- P6: GEMM3 (M=32, N=128, K=128) + bias -> bf16 Cagg LDS
    {
        f32x4 acc3[2][2];
        #pragma unroll
        for (int mt = 0; mt < 2; ++mt)
            #pragma unroll
            for (int nt = 0; nt < 2; ++nt) acc3[mt][nt] = zero4;
        for (int ks = 0; ks < 4; ++ks) {
            bf16x8 af0 = *(const bf16x8*)&frag_s[fragOff(ks, 0, lane)];
            bf16x8 af1 = *(const bf16x8*)&frag_s[fragOff(ks, 1, lane)];
            int krow = ks * 32 + quad * 8;
            #pragma unroll
            for (int nt = 0; nt < 2; ++nt) {
                int n = n0w + nt * 16 + lr;
                bf16x8 bw = *(const bf16x8*)&We3T[n * KP2 + krow];
                acc3[0][nt] = __builtin_amdgcn_mfma_f32_16x16x32_bf16(af0, bw, acc3[0][nt], 0, 0, 0);
                acc3[1][nt] = __builtin_amdgcn_mfma_f32_16x16x32_bf16(af1, bw, acc3[1][nt], 0, 0, 0);
            }
        }
        #pragma unroll
        for (int nt = 0; nt < 2; ++nt) {
            int n = n0w + nt * 16 + lr;
            float b3 = be3[n];
            #pragma unroll
            for (int mt = 0; mt < 2; ++mt) {
                int mb = mt * 16 + quad * 4;
                unsigned int u0 = f2bf_pk(acc3[mt][nt][0] + b3, acc3[mt][nt][1] + b3);
                unsigned int u1 = f2bf_pk(acc3[mt][nt][2] + b3, acc3[mt][nt][3] + b3);
                cagg_s[(mb + 0) * CAGS + n] = (unsigned short)(u0 & 0xFFFFu);
                cagg_s[(mb + 1) * CAGS + n] = (unsigned short)(u0 >> 16);
                cagg_s[(mb + 2) * CAGS + n] = (unsigned short)(u1 & 0xFFFFu);
                cagg_s[(mb + 3) * CAGS + n] = (unsigned short)(u1 >> 16);
            }
        }
    }
    __syncthreads();

    // ---- P7: dst-run segmented atomic flush (rows sorted by dst)
    {
        const int c = tid & 127, h = tid >> 7;
        const int m0 = h * 16;
        float run = bfu2f(cagg_s[m0 * CAGS + c]);
        int curd = dst_s[m0];
        #pragma unroll
        for (int m = m0 + 1; m < m0 + 16; ++m) {
            int d = dst_s[m];
            float v = bfu2f(cagg_s[m * CAGS + c]);
            if (d == curd) run += v;
            else { atomAddF(&mh[(size_t)curd * HID + c], run); curd = d; run = v; }
        }
        atomAddF(&mh[(size_t)curd * HID + c], run);
    }
    // ---- P8: m_v segmented flush
    if (tid < 2) {
        const int c = tid;
        float run = vw_s[0] * rel_s[c];
        int curd = dst_s[0];
        for (int m = 1; m < TE; ++m) {
            int d = dst_s[m];
            float v = vw_s[m] * rel_s[2 * m + c];
            if (d == curd) run += v;
            else { atomAddF(&mv[2 * curd + c], run); curd = d; run = v; }
        }
        atomAddF(&mv[2 * curd + c], run);
    }
}

// ---------------------------------------------------------------- node kernel (MFMA)
__global__ __launch_bounds__(256, 7)
void eg_node(const float* __restrict__ x,
             const float* __restrict__ bh1, const float* __restrict__ gh1,
             const float* __restrict__ bth1, const float* __restrict__ bh2,
             const float* __restrict__ mh, const float* __restrict__ mv,
             const int* __restrict__ deg, const short* __restrict__ wt,
             float* __restrict__ out)
{
    __shared__ __align__(16) short frag_s[7 * 2 * 64 * 8];   // 14336 B
    __shared__ float psum_s[256];
    __shared__ float mu_s[32], rs_s[32];
    __shared__ float rden_s[TN], norm_s[TN];

    const int tid  = threadIdx.x;
    const int lane = tid & 63;
    const int wid  = tid >> 6;
    const int lr   = lane & 15;
    const int quad = lane >> 4;
    const int n0w  = wid * 32;
    const int n_base = blockIdx.x * TN;   // NNODE % TN == 0

    const short* Wh1T = wt + WT_WH1;
    const short* Wh2T = wt + WT_WH2;

    // ---- P0: den/norm + zero ks=6 frag region
    if (tid < TN) {
        int n = n_base + tid;
        float den = fmaxf((float)deg[n], 1.0f);
        float rd = 1.0f / den;
        float ax = mv[2 * n] * rd + 1e-8f;
        float ay = mv[2 * n + 1] * rd + 1e-8f;
        rden_s[tid] = rd;
        norm_s[tid] = sqrtf(ax * ax + ay * ay);
    }
    if (tid < 128) {
        int4 z = {0, 0, 0, 0};
        *(int4*)&frag_s[6 * 2 * 64 * 8 + tid * 8] = z;
    }
    __syncthreads();

    // ---- P1: stage [x | mh/den | norm] into A1 fragments
    {
        const int e = tid & 31, slot = tid >> 5;
        const int n = n_base + e;
        // x: k 0..63, octet o = slot
        {
            int c0 = slot * 8;
            const float4 a0 = *(const float4*)&x[(size_t)n * NCH + c0];
            const float4 a1 = *(const float4*)&x[(size_t)n * NCH + c0 + 4];
            uint4 pk;
            pk.x = f2bf_pk(a0.x, a0.y); pk.y = f2bf_pk(a0.z, a0.w);
            pk.z = f2bf_pk(a1.x, a1.y); pk.w = f2bf_pk(a1.z, a1.w);
            int ks = slot >> 2, kq = slot & 3;
            *(uint4*)&frag_s[fragOff(ks, e >> 4, kq * 16 + (e & 15))] = pk;
        }
        // mh/den: k 64..191, octets 8..23
        float rd = rden_s[e];
        #pragma unroll
        for (int h = 0; h < 2; ++h) {
            int o = 8 + slot + h * 8;
            int k0 = (o - 8) * 8;
            const float4 a0 = *(const float4*)&mh[(size_t)n * HID + k0];
            const float4 a1 = *(const float4*)&mh[(size_t)n * HID + k0 + 4];
            uint4 pk;
            pk.x = f2bf_pk(a0.x * rd, a0.y * rd); pk.y = f2bf_pk(a0.z * rd, a0.w * rd);
            pk.z = f2bf_pk(a1.x * rd, a1.y * rd); pk.w = f2bf_pk(a1.z * rd, a1.w * rd);
            int ks = o >> 2, kq = o & 3;
            *(uint4*)&frag_s[fragOff(ks, e >> 4, kq * 16 + (e & 15))] = pk;
        }
    }
    if (tid < TN) {   // norm at k=192 (ks=6, kq=0, j=0)
        frag_s[fragOff(6, tid >> 4, (tid & 15))] = (short)f2bf(norm_s[tid]);
    }
    __syncthreads();

    const int ncol0 = n0w + lr;
    const int ncol1 = n0w + 16 + lr;

    // ---- P2: GEMM1 (M=32, N=128, K=224)
    f32x4 zero4 = {0.f, 0.f, 0.f, 0.f};
    f32x4 acc1[2][2];
    #pragma unroll
    for (int mt = 0; mt < 2; ++mt)
        #pragma unroll
        for (int nt = 0; nt < 2; ++nt) acc1[mt][nt] = zero4;
    for (int ks = 0; ks < 7; ++ks) {
        bf16x8 af0 = *(const bf16x8*)&frag_s[fragOff(ks, 0, lane)];
        bf16x8 af1 = *(const bf16x8*)&frag_s[fragOff(ks, 1, lane)];
        int krow = ks * 32 + quad * 8;
        #pragma unroll
        for (int nt = 0; nt < 2; ++nt) {
            int n = n0w + nt * 16 + lr;
            bf16x8 bw = *(const bf16x8*)&Wh1T[n * KN1 + krow];
            acc1[0][nt] = __builtin_amdgcn_mfma_f32_16x16x32_bf16(af0, bw, acc1[0][nt], 0, 0, 0);
            acc1[1][nt] = __builtin_amdgcn_mfma_f32_16x16x32_bf16(af1, bw, acc1[1][nt], 0, 0, 0);
        }
    }
    {
        float b0 = bh1[ncol0], b1 = bh1[ncol1];
        #pragma unroll
        for (int mt = 0; mt < 2; ++mt)
            #pragma unroll
            for (int r = 0; r < 4; ++r) { acc1[mt][0][r] += b0; acc1[mt][1][r] += b1; }
    }

    // ---- P3: LN stats
    #pragma unroll
    for (int mt = 0; mt < 2; ++mt)
        #pragma unroll
        for (int r = 0; r < 4; ++r) {
            float s = acc1[mt][0][r] + acc1[mt][1][r];
            float q = acc1[mt][0][r] * acc1[mt][0][r] + acc1[mt][1][r] * acc1[mt][1][r];
            #pragma unroll
            for (int m = 1; m < 16; m <<= 1) {
                s += __shfl_xor(s, m, 16);
                q += __shfl_xor(q, m, 16);
            }
            if (lr == 0) {
                int row = mt * 16 + quad * 4 + r;
                psum_s[row * 4 + wid]       = s;
                psum_s[128 + row * 4 + wid] = q;
            }
        }
    __syncthreads();
    if (tid < 32) {
        float s = 0.f, q = 0.f;
        #pragma unroll
        for (int w = 0; w < 4; ++w) {
            s += psum_s[tid * 4 + w];
            q += psum_s[128 + tid * 4 + w];
        }
        float mu = s * (1.0f / HID);
        float var = q * (1.0f / HID) - mu * mu;
        mu_s[tid] = mu;
        rs_s[tid] = rsqrtf(var + LN_EPS);
    }
    __syncthreads();

    // ---- P4: normalize + softplus -> A2 fragments (K=128)
    {
        float g0 = gh1[ncol0], g1 = gh1[ncol1];
        float t0 = bth1[ncol0], t1 = bth1[ncol1];
        int ks0 = ncol0 >> 5, kq0 = (ncol0 & 31) >> 3, j0 = ncol0 & 7;
        int ks1 = ncol1 >> 5, kq1 = (ncol1 & 31) >> 3, j1 = ncol1 & 7;
        int fo0 = (ks0 * 128 + kq0 * 16) * 8 + j0;
        int fo1 = (ks1 * 128 + kq1 * 16) * 8 + j1;
        #pragma unroll
        for (int mt = 0; mt < 2; ++mt)
            #pragma unroll
            for (int r = 0; r < 4; ++r) {
                int rlow = quad * 4 + r, row = mt * 16 + rlow;
                float mu = mu_s[row], rsv = rs_s[row];
                float h0 = sp((acc1[mt][0][r] - mu) * rsv * g0 + t0);
                float h1 = sp((acc1[mt][1][r] - mu) * rsv * g1 + t1);
                unsigned int ph = f2bf_pk(h0, h1);
                frag_s[fo0 + (mt * 64 + rlow) * 8] = (short)(ph & 0xFFFFu);
                frag_s[fo1 + (mt * 64 + rlow) * 8] = (short)(ph >> 16);
            }
    }
    __syncthreads();

    // ---- P5: GEMM2 (M=32, N=64, K=128): each wave computes 16 cols
    {
        const int col = wid * 16 + lr;
        f32x4 acc2[2] = { zero4, zero4 };
        for (int ks = 0; ks < 4; ++ks) {
            bf16x8 af0 = *(const bf16x8*)&frag_s[fragOff(ks, 0, lane)];
            bf16x8 af1 = *(const bf16x8*)&frag_s[fragOff(ks, 1, lane)];
            int krow = ks * 32 + quad * 8;
            bf16x8 bw = *(const bf16x8*)&Wh2T[col * KP2 + krow];
            acc2[0] = __builtin_amdgcn_mfma_f32_16x16x32_bf16(af0, bw, acc2[0], 0, 0, 0);
            acc2[1] = __builtin_amdgcn_mfma_f32_16x16x32_bf16(af1, bw, acc2[1], 0, 0, 0);
        }
        float bo = bh2[col];
        #pragma unroll
        for (int mt = 0; mt < 2; ++mt)
            #pragma unroll
            for (int r = 0; r < 4; ++r) {
                int m = mt * 16 + quad * 4 + r;
                size_t idx = (size_t)(n_base + m) * OUTC + col;
                out[idx] = x[(size_t)(n_base + m) * NCH + col] + acc2[mt][r] + bo;
            }
    }
}

// ---------------------------------------------------------------- launch
extern "C" void kernel_launch(void* const* d_in, const int* in_sizes, int n_in,
                              void* d_out, int out_size, void* d_ws, size_t ws_size,
                              hipStream_t stream)
{
    const float* x    = (const float*)d_in[0];
    const float* pos  = (const float*)d_in[1];
    const float* vel  = (const float*)d_in[2];
    const float* We1  = (const float*)d_in[3];
    const float* be1  = (const float*)d_in[4];
    const float* ge1  = (const float*)d_in[5];
    const float* bte1 = (const float*)d_in[6];
    const float* We2  = (const float*)d_in[7];
    const float* be2  = (const float*)d_in[8];
    const float* We3  = (const float*)d_in[9];
    const float* be3  = (const float*)d_in[10];
    const float* Wv1  = (const float*)d_in[11];
    const float* bv1  = (const float*)d_in[12];
    const float* gv1  = (const float*)d_in[13];
    const float* btv1 = (const float*)d_in[14];
    const float* Wv2  = (const float*)d_in[15];
    const float* bv2  = (const float*)d_in[16];
    const float* Wh1  = (const float*)d_in[17];
    const float* bh1  = (const float*)d_in[18];
    const float* gh1  = (const float*)d_in[19];
    const float* bth1 = (const float*)d_in[20];
    const float* Wh2  = (const float*)d_in[21];
    const float* bh2  = (const float*)d_in[22];
    const int*   ei   = (const int*)d_in[23];

    // workspace layout
    float* mh   = (float*)d_ws;                      // 2,560,000 f
    float* mv   = mh + (size_t)NNODE * HID;          // 40,000 f
    int*   deg  = (int*)(mv + NNODE * 2);            // 20,000 i
    int*   cur  = deg + NNODE;                       // 20,000 i
    int*   perm = cur + NNODE;                       // 640,000 i
    short* wt   = (short*)(perm + NEDGE);            // 110,592 s

    // zero mh, mv, deg (contiguous)
    size_t zbytes = ((size_t)NNODE * HID + NNODE * 2 + NNODE) * sizeof(float);
    hipMemsetAsync(d_ws, 0, zbytes, stream);

    eg_prep<<<dim3((WT_TOTAL + 255) / 256), dim3(256), 0, stream>>>(
        We1, Wv1, We2, We3, Wh1, Wh2, wt);
    eg_hist<<<dim3(NEDGE / 256), dim3(256), 0, stream>>>(ei, deg);
    eg_scan<<<dim3(1), dim3(1024), 0, stream>>>(deg, cur);
    eg_scatter<<<dim3(NEDGE / 256), dim3(256), 0, stream>>>(ei, cur, perm);

    eg_edge<<<dim3(NEDGE / TE), dim3(256), 0, stream>>>(
        x, pos, vel, be1, ge1, bte1, be2, be3,
        bv1, gv1, btv1, Wv2, bv2, wt, ei, perm, mh, mv);

    eg_node<<<dim3(NNODE / TN), dim3(256), 0, stream>>>(
        x, bh1, gh1, bth1, bh2, mh, mv, deg, wt, (float*)d_out);
}

// Round 8
// 517.744 us; speedup vs baseline: 4.9754x; 1.0478x over previous
//
#include <hip/hip_runtime.h>
#include <stdint.h>

#define NCH    64
#define HID    128
#define OUTC   64
#define NNODE  20000
#define NEDGE  640000
#define FDIM   133
#define TE     32
#define TN     32
#define LN_EPS 1e-5f
#define KP1    160          // K of edge GEMM1, padded (133 -> 160 = 5*32)
#define KP2    128          // K of edge GEMM2/3
#define KN1    224          // K of node GEMM1, padded (193 -> 224 = 7*32)
#define CAGS   130          // bf16 Cagg LDS row stride (shorts)
#define NEBLK  (NEDGE / TE) // 20000 edge blocks
#define XSTR   (NEBLK / 8)  // 2500 blocks per XCD slice

typedef __attribute__((ext_vector_type(8))) short bf16x8;
typedef __attribute__((ext_vector_type(4))) float f32x4;

__device__ __forceinline__ unsigned short f2bf(float f) {
    union { float f; unsigned int i; } v; v.f = f;
    unsigned int b = v.i;
    return (unsigned short)((b + 0x7FFFu + ((b >> 16) & 1u)) >> 16);
}
#if defined(__has_builtin)
#if __has_builtin(__builtin_amdgcn_cvt_pk_bf16_f32)
#define HAVE_PK_BF16 1
#endif
#endif
__device__ __forceinline__ unsigned int f2bf_pk(float a, float b) {
#ifdef HAVE_PK_BF16
    auto r = __builtin_amdgcn_cvt_pk_bf16_f32(a, b);
    return __builtin_bit_cast(unsigned int, r);
#else
    return (unsigned int)f2bf(a) | ((unsigned int)f2bf(b) << 16);
#endif
}
__device__ __forceinline__ float bfu2f(unsigned short u) {
    union { unsigned int i; float f; } v; v.i = ((unsigned int)u) << 16; return v.f;
}
// fast softplus: hardware v_exp_f32 / v_log_f32
__device__ __forceinline__ float sp(float xv) {
    return fmaxf(xv, 0.f) + __logf(1.0f + __expf(-fabsf(xv)));
}
__device__ __forceinline__ void atomAddF(float* p, float v) {
    __hip_atomic_fetch_add(p, v, __ATOMIC_RELAXED, __HIP_MEMORY_SCOPE_AGENT);
}
// xor-butterfly via ds_swizzle with immediate pattern (no lane math)
template<int PAT> __device__ __forceinline__ float shx(float v) {
    int i = __builtin_amdgcn_ds_swizzle(__builtin_bit_cast(int, v), PAT);
    return __builtin_bit_cast(float, i);
}
#define RED16(v) { v += shx<0x041F>(v); v += shx<0x081F>(v); v += shx<0x101F>(v); v += shx<0x201F>(v); }

// A/B fragment offset in a [kstep][mtile(2)][lane(64)][8] bf16 buffer
__device__ __forceinline__ int fragOff(int ks, int mt, int lanepos) {
    return ((ks * 2 + mt) * 64 + lanepos) * 8;
}

#define WT_WE1 0
#define WT_WV1 (128 * KP1)
#define WT_WE2 (2 * 128 * KP1)
#define WT_WE3 (2 * 128 * KP1 + 128 * KP2)
#define WT_WH1 (2 * 128 * KP1 + 2 * 128 * KP2)            // 73728
#define WT_WH2 (WT_WH1 + 128 * KN1)                        // +28672
#define WT_TOTAL (WT_WH2 + 64 * KP2)                       // 110592 shorts
#define PKP_N  1153                                        // packed param floats

// --------------------------- fused: weight transpose + param pack + histogram
__global__ __launch_bounds__(256)
void eg_prep(const float* __restrict__ We1, const float* __restrict__ Wv1,
             const float* __restrict__ We2, const float* __restrict__ We3,
             const float* __restrict__ Wh1, const float* __restrict__ Wh2,
             const float* __restrict__ be1, const float* __restrict__ bv1,
             const float* __restrict__ ge1, const float* __restrict__ bte1,
             const float* __restrict__ gv1, const float* __restrict__ btv1,
             const float* __restrict__ Wv2, const float* __restrict__ be2,
             const float* __restrict__ be3, const float* __restrict__ bv2,
             const int* __restrict__ ei,
             short* __restrict__ wt, float* __restrict__ pkp,
             int* __restrict__ deg)
{
    int idx = blockIdx.x * 256 + threadIdx.x;
    if (idx < WT_TOTAL) {
        short v;
        if (idx < WT_WV1) {
            int n = idx / KP1, k = idx % KP1;
            v = (k < FDIM) ? (short)f2bf(We1[(size_t)k * HID + n]) : (short)0;
        } else if (idx < WT_WE2) {
            int r = idx - WT_WV1; int n = r / KP1, k = r % KP1;
            v = (k < FDIM) ? (short)f2bf(Wv1[(size_t)k * HID + n]) : (short)0;
        } else if (idx < WT_WE3) {
            int r = idx - WT_WE2; int n = r / KP2, k = r % KP2;
            v = (short)f2bf(We2[(size_t)k * HID + n]);
        } else if (idx < WT_WH1) {
            int r = idx - WT_WE3; int n = r / KP2, k = r % KP2;
            v = (short)f2bf(We3[(size_t)k * HID + n]);
        } else if (idx < WT_WH2) {
            int r = idx - WT_WH1; int n = r / KN1, k = r % KN1;
            v = (k < 193) ? (short)f2bf(Wh1[(size_t)k * HID + n]) : (short)0;
        } else {
            int r = idx - WT_WH2; int n = r / KP2, k = r % KP2;
            v = (short)f2bf(Wh2[(size_t)k * OUTC + n]);
        }
        wt[idx] = v;
    }
    if (idx < PKP_N) {
        float pv;
        int k = idx >> 7, c = idx & 127;
        switch (k) {
            case 0: pv = be1[c]; break;
            case 1: pv = bv1[c]; break;
            case 2: pv = ge1[c]; break;
            case 3: pv = bte1[c]; break;
            case 4: pv = gv1[c]; break;
            case 5: pv = btv1[c]; break;
            case 6: pv = Wv2[c]; break;
            case 7: pv = be2[c]; break;
            case 8: pv = be3[c]; break;
            default: pv = bv2[0]; break;   // idx == 1152
        }
        pkp[idx] = pv;
    }
    if (idx < NEDGE)
        __hip_atomic_fetch_add(&deg[ei[NEDGE + idx]], 1, __ATOMIC_RELAXED, __HIP_MEMORY_SCOPE_AGENT);
}

// ------------------------------------------------- exclusive scan -> cursor
__global__ __launch_bounds__(1024)
void eg_scan(const int* __restrict__ deg, int* __restrict__ cur)
{
    __shared__ int part[1024];
    const int tid = threadIdx.x;
    const int chunk = (NNODE + 1023) / 1024;   // 20
    const int base = tid * chunk;
    const int lim = min(base + chunk, NNODE);
    int s = 0;
    for (int j = base; j < lim; ++j) s += deg[j];
    part[tid] = s;
    __syncthreads();
    for (int off = 1; off < 1024; off <<= 1) {
        int v = (tid >= off) ? part[tid - off] : 0;
        __syncthreads();
        part[tid] += v;
        __syncthreads();
    }
    int run = (tid > 0) ? part[tid - 1] : 0;
    for (int j = base; j < lim; ++j) { cur[j] = run; run += deg[j]; }
}

// ------------------------------------------------- dst-sorted permutation
__global__ __launch_bounds__(256)
void eg_scatter(const int* __restrict__ ei, int* __restrict__ cur,
                int* __restrict__ perm)
{
    int i = blockIdx.x * 256 + threadIdx.x;
    if (i < NEDGE) {
        int d = ei[NEDGE + i];
        int p = __hip_atomic_fetch_add(&cur[d], 1, __ATOMIC_RELAXED, __HIP_MEMORY_SCOPE_AGENT);
        perm[p] = i;
    }
}

// ---------------------------------------------------------------- edge kernel
__global__ __launch_bounds__(256, 7)
void eg_edge(const float* __restrict__ x, const float* __restrict__ pos,
             const float* __restrict__ vel,
             const float* __restrict__ pkp,
             const short* __restrict__ wt,
             const int* __restrict__ ei, const int* __restrict__ perm,
             float* __restrict__ mh, float* __restrict__ mv)
{
    __shared__ __align__(16) short frag_s[5 * 2 * 64 * 8];        // 10240 B
    __shared__ __align__(4) unsigned short cagg_s[TE * CAGS];     // 8320 B
    __shared__ float psum_s[512];                                  // 2048 B
    __shared__ float mu_s[64], rs_s[64];
    __shared__ int   dst_s[TE], src_s[TE];
    __shared__ float rel_s[TE * 2], vw_s[TE];

    const int tid  = threadIdx.x;
    const int lane = tid & 63;
    const int wid  = tid >> 6;
    const int lr   = lane & 15;
    const int quad = lane >> 4;
    const int n0w  = wid * 32;
    // XCD-aware swizzle: XCD (bid & 7) gets a CONTIGUOUS dst-sorted slice,
    // so its mh slice (~1.3 MB) and x[dst] rows stay resident in its 4 MB L2.
    const int bid  = (blockIdx.x & 7) * XSTR + (blockIdx.x >> 3);
    const int e_base = bid * TE;

    const short* We1T = wt + WT_WE1;
    const short* Wv1T = wt + WT_WV1;
    const short* We2T = wt + WT_WE2;
    const short* We3T = wt + WT_WE3;

    // ---- P0: permuted indices + geometry, zero kstep-4 frag region
    float geo[5];
    if (tid < TE) {
        int gi = perm[e_base + tid];
        int eS = ei[gi];
        int eD = ei[NEDGE + gi];
        src_s[tid] = eS; dst_s[tid] = eD;
        float rx = pos[2 * eS]     - pos[2 * eD];
        float ry = pos[2 * eS + 1] - pos[2 * eD + 1];
        float vx = vel[2 * eS]     - vel[2 * eD];
        float vy = vel[2 * eS + 1] - vel[2 * eD + 1];
        float dsq = rx * rx + ry * ry;
        float dvr = vx * rx + vy * ry;
        float r2  = fminf(1.0f / (dsq + 0.05f), 20.0f);
        float r6  = fminf(r2 * r2 * r2, 400.0f);
        float r12 = fminf(r6 * r6, 160000.0f);
        geo[0] = dsq; geo[1] = dvr; geo[2] = r2; geo[3] = r6; geo[4] = r12;
        rel_s[2 * tid] = rx; rel_s[2 * tid + 1] = ry;
    }
    if (tid < 128) {
        int4 z = {0, 0, 0, 0};
        *(int4*)&frag_s[4 * 2 * 64 * 8 + tid * 8] = z;
    }
    __syncthreads();

    // ---- P1: geo + gather x into A1 fragments (packed bf16)
    if (tid < TE) {
        int off = fragOff(4, tid >> 4, (tid & 15));
        #pragma unroll
        for (int j = 0; j < 5; ++j) frag_s[off + j] = (short)f2bf(geo[j]);
    }
    {
        const int e = tid & 31, slot = tid >> 5;
        const int d = dst_s[e], s = src_s[e];
        #pragma unroll
        for (int h = 0; h < 2; ++h) {
            int o = slot + h * 8;
            int node = h ? s : d;
            int c0 = (o & 7) * 8;
            const float4 a0 = *(const float4*)&x[(size_t)node * NCH + c0];
            const float4 a1 = *(const float4*)&x[(size_t)node * NCH + c0 + 4];
            uint4 pk;
            pk.x = f2bf_pk(a0.x, a0.y); pk.y = f2bf_pk(a0.z, a0.w);
            pk.z = f2bf_pk(a1.x, a1.y); pk.w = f2bf_pk(a1.z, a1.w);
            int ks = o >> 2, kq = o & 3;
            *(uint4*)&frag_s[fragOff(ks, e >> 4, kq * 16 + (e & 15))] = pk;
        }
    }
    __syncthreads();

    const int ncol0 = n0w + lr;
    const int ncol1 = n0w + 16 + lr;
    const float* p0 = pkp + ncol0;     // single base, imm offsets k*128
    const float* p1 = pkp + ncol1;

    // ---- P2: dual GEMM1 via MFMA (M=32, N=128, K=160)
    f32x4 zero4 = {0.f, 0.f, 0.f, 0.f};
    f32x4 accE[2][2], accV[2][2];
    #pragma unroll
    for (int mt = 0; mt < 2; ++mt)
        #pragma unroll
        for (int nt = 0; nt < 2; ++nt) { accE[mt][nt] = zero4; accV[mt][nt] = zero4; }
    {
        const short* pa = &frag_s[lane * 8];
        const short* pwE0 = We1T + ncol0 * KP1 + quad * 8;
        const short* pwE1 = We1T + ncol1 * KP1 + quad * 8;
        const short* pwV0 = Wv1T + ncol0 * KP1 + quad * 8;
        const short* pwV1 = Wv1T + ncol1 * KP1 + quad * 8;
        #pragma unroll
        for (int ks = 0; ks < 5; ++ks) {
            bf16x8 af0 = *(const bf16x8*)&pa[ks * 1024];
            bf16x8 af1 = *(const bf16x8*)&pa[ks * 1024 + 512];
            bf16x8 bwE0 = *(const bf16x8*)&pwE0[ks * 32];
            bf16x8 bwE1 = *(const bf16x8*)&pwE1[ks * 32];
            bf16x8 bwV0 = *(const bf16x8*)&pwV0[ks * 32];
            bf16x8 bwV1 = *(const bf16x8*)&pwV1[ks * 32];
            accE[0][0] = __builtin_amdgcn_mfma_f32_16x16x32_bf16(af0, bwE0, accE[0][0], 0, 0, 0);
            accE[1][0] = __builtin_amdgcn_mfma_f32_16x16x32_bf16(af1, bwE0, accE[1][0], 0, 0, 0);
            accE[0][1] = __builtin_amdgcn_mfma_f32_16x16x32_bf16(af0, bwE1, accE[0][1], 0, 0, 0);
            accE[1][1] = __builtin_amdgcn_mfma_f32_16x16x32_bf16(af1, bwE1, accE[1][1], 0, 0, 0);
            accV[0][0] = __builtin_amdgcn_mfma_f32_16x16x32_bf16(af0, bwV0, accV[0][0], 0, 0, 0);
            accV[1][0] = __builtin_amdgcn_mfma_f32_16x16x32_bf16(af1, bwV0, accV[1][0], 0, 0, 0);
            accV[0][1] = __builtin_amdgcn_mfma_f32_16x16x32_bf16(af0, bwV1, accV[0][1], 0, 0, 0);
            accV[1][1] = __builtin_amdgcn_mfma_f32_16x16x32_bf16(af1, bwV1, accV[1][1], 0, 0, 0);
        }
    }
    {
        float be0 = p0[0], be_1 = p1[0];
        float bv0 = p0[128], bv_1 = p1[128];
        #pragma unroll
        for (int mt = 0; mt < 2; ++mt)
            #pragma unroll
            for (int r = 0; r < 4; ++r) {
                accE[mt][0][r] += be0; accE[mt][1][r] += be_1;
                accV[mt][0][r] += bv0; accV[mt][1][r] += bv_1;
            }
    }

    // ---- P3: LN stats in-register (ds_swizzle butterflies, imm patterns)
    #pragma unroll
    for (int mt = 0; mt < 2; ++mt)
        #pragma unroll
        for (int r = 0; r < 4; ++r) {
            float se = accE[mt][0][r] + accE[mt][1][r];
            float qe = accE[mt][0][r] * accE[mt][0][r] + accE[mt][1][r] * accE[mt][1][r];
            float sv = accV[mt][0][r] + accV[mt][1][r];
            float qv = accV[mt][0][r] * accV[mt][0][r] + accV[mt][1][r] * accV[mt][1][r];
            RED16(se); RED16(qe); RED16(sv); RED16(qv);
            if (lr == 0) {
                int row = mt * 16 + quad * 4 + r;
                psum_s[      row * 4 + wid] = se;
                psum_s[128 + row * 4 + wid] = qe;
                psum_s[256 + row * 4 + wid] = sv;
                psum_s[384 + row * 4 + wid] = qv;
            }
        }
    __syncthreads();
    if (tid < 64) {
        int p = tid >> 5, row = tid & 31;
        float s = 0.f, q = 0.f;
        #pragma unroll
        for (int w = 0; w < 4; ++w) {
            s += psum_s[p * 256 +       row * 4 + w];
            q += psum_s[p * 256 + 128 + row * 4 + w];
        }
        float mu = s * (1.0f / HID);
        float var = q * (1.0f / HID) - mu * mu;
        mu_s[p * 32 + row] = mu;
        rs_s[p * 32 + row] = rsqrtf(var + LN_EPS);
    }
    __syncthreads();

    // ---- P4: normalize in-register; E -> A2 frags, V -> vw partials
    {
        float gE0 = p0[256], gE1 = p1[256];
        float tE0 = p0[384], tE1 = p1[384];
        float gV0 = p0[512], gV1 = p1[512];
        float tV0 = p0[640], tV1 = p1[640];
        float w20 = p0[768], w21 = p1[768];
        int ks0 = ncol0 >> 5, kq0 = (ncol0 & 31) >> 3, j0 = ncol0 & 7;
        int ks1 = ncol1 >> 5, kq1 = (ncol1 & 31) >> 3, j1 = ncol1 & 7;
        short* bp0 = &frag_s[(ks0 * 128 + kq0 * 16 + quad * 4) * 8 + j0];
        short* bp1 = &frag_s[(ks1 * 128 + kq1 * 16 + quad * 4) * 8 + j1];
        #pragma unroll
        for (int mt = 0; mt < 2; ++mt)
            #pragma unroll
            for (int r = 0; r < 4; ++r) {
                int rlow = quad * 4 + r, row = mt * 16 + rlow;
                float mu = mu_s[row], rsv = rs_s[row];
                float muV = mu_s[32 + row], rsV = rs_s[32 + row];
                float h0 = sp((accE[mt][0][r] - mu) * rsv * gE0 + tE0);
                float h1 = sp((accE[mt][1][r] - mu) * rsv * gE1 + tE1);
                unsigned int ph = f2bf_pk(h0, h1);
                bp0[mt * 512 + r * 8] = (short)(ph & 0xFFFFu);
                bp1[mt * 512 + r * 8] = (short)(ph >> 16);
                float v0 = sp((accV[mt][0][r] - muV) * rsV * gV0 + tV0);
                float v1 = sp((accV[mt][1][r] - muV) * rsV * gV1 + tV1);
                float vp = v0 * w20 + v1 * w21;
                RED16(vp);
                if (lr == 0) psum_s[row * 4 + wid] = vp;
            }
    }
    __syncthreads();
    if (tid < TE) {
        float s = 0.f;
        #pragma unroll
        for (int w = 0; w < 4; ++w) s += psum_s[tid * 4 + w];
        vw_s[tid] = s + pkp[1152];
    }

    // ---- P5: GEMM2 (M=32, N=128, K=128) + softplus -> A3 fragments
    {
        f32x4 acc2[2][2];
        #pragma unroll
        for (int mt = 0; mt < 2; ++mt)
            #pragma unroll
            for (int nt = 0; nt < 2; ++nt) acc2[mt][nt] = zero4;
        {
            const short* pa = &frag_s[lane * 8];
            const short* pw0 = We2T + ncol0 * KP2 + quad * 8;
            const short* pw1 = We2T + ncol1 * KP2 + quad * 8;
            #pragma unroll
            for (int ks = 0; ks < 4; ++ks) {
                bf16x8 af0 = *(const bf16x8*)&pa[ks * 1024];
                bf16x8 af1 = *(const bf16x8*)&pa[ks * 1024 + 512];
                bf16x8 bw0 = *(const bf16x8*)&pw0[ks * 32];
                bf16x8 bw1 = *(const bf16x8*)&pw1[ks * 32];
                acc2[0][0] = __builtin_amdgcn_mfma_f32_16x16x32_bf16(af0, bw0, acc2[0][0], 0, 0, 0);
                acc2[1][0] = __builtin_amdgcn_mfma_f32_16x16x32_bf16(af1, bw0, acc2[1][0], 0, 0, 0);
                acc2[0][1] = __builtin_amdgcn_mfma_f32_16x16x32_bf16(af0, bw1, acc2[0][1], 0, 0, 0);
                acc2[1][1] = __builtin_amdgcn_mfma_f32_16x16x32_bf16(af1, bw1, acc2[1][1], 0, 0, 0);
            }
        }
        __syncthreads();   // all A2 reads done before overwriting with A3
        float b2a = p0[896], b2b = p1[896];
        int ksA = ncol0 >> 5, kqA = (ncol0 & 31) >> 3, jA = ncol0 & 7;
        int ksB = ncol1 >> 5, kqB = (ncol1 & 31) >> 3, jB = ncol1 & 7;
        short* bpA = &frag_s[(ksA * 128 + kqA * 16 + quad * 4) * 8 + jA];
        short* bpB = &frag_s[(ksB * 128 + kqB * 16 + quad * 4) * 8 + jB];
        #pragma unroll
        for (int mt = 0; mt < 2; ++mt)
            #pragma unroll
            for (int r = 0; r < 4; ++r) {
                bpA[mt * 512 + r * 8] = (short)f2bf(sp(acc2[mt][0][r] + b2a));
                bpB[mt * 512 + r * 8] = (short)f2bf(sp(acc2[mt][1][r] + b2b));
            }
    }
    __syncthreads();

    // ---- P6: GEMM3 (M=32, N=128, K=128) + bias -> bf16 Cagg LDS
    {
        f32x4 acc3[2][2];
        #pragma unroll
        for (int mt = 0; mt < 2; ++mt)
            #pragma unroll
            for (int nt = 0; nt < 2; ++nt) acc3[mt][nt] = zero4;
        {
            const short* pa = &frag_s[lane * 8];
            const short* pw0 = We3T + ncol0 * KP2 + quad * 8;
            const short* pw1 = We3T + ncol1 * KP2 + quad * 8;
            #pragma unroll
            for (int ks = 0; ks < 4; ++ks) {
                bf16x8 af0 = *(const bf16x8*)&pa[ks * 1024];
                bf16x8 af1 = *(const bf16x8*)&pa[ks * 1024 + 512];
                bf16x8 bw0 = *(const bf16x8*)&pw0[ks * 32];
                bf16x8 bw1 = *(const bf16x8*)&pw1[ks * 32];
                acc3[0][0] = __builtin_amdgcn_mfma_f32_16x16x32_bf16(af0, bw0, acc3[0][0], 0, 0, 0);
                acc3[1][0] = __builtin_amdgcn_mfma_f32_16x16x32_bf16(af1, bw0, acc3[1][0], 0, 0, 0);
                acc3[0][1] = __builtin_amdgcn_mfma_f32_16x16x32_bf16(af0, bw1, acc3[0][1], 0, 0, 0);
                acc3[1][1] = __builtin_amdgcn_mfma_f32_16x16x32_bf16(af1, bw1, acc3[1][1], 0, 0, 0);
            }
        }
        float b3a = p0[1024], b3b = p1[1024];
        unsigned short* bpA = &cagg_s[(quad * 4) * CAGS + ncol0];
        unsigned short* bpB = &cagg_s[(quad * 4) * CAGS + ncol1];
        #pragma unroll
        for (int mt = 0; mt < 2; ++mt)
            #pragma unroll
            for (int r = 0; r < 4; ++r) {
                bpA[(mt * 16 + r) * CAGS] = f2bf(acc3[mt][0][r] + b3a);
                bpB[(mt * 16 + r) * CAGS] = f2bf(acc3[mt][1][r] + b3b);
            }
    }
    __syncthreads();

    // ---- P7: dst-run segmented atomic flush (rows sorted by dst)
    {
        const int c = tid & 127, h = tid >> 7;
        const unsigned short* cp = &cagg_s[(h * 16) * CAGS + c];
        const int m0 = h * 16;
        float run = bfu2f(cp[0]);
        int curd = dst_s[m0];
        #pragma unroll
        for (int m = 1; m < 16; ++m) {
            int d = dst_s[m0 + m];
            float v = bfu2f(cp[m * CAGS]);
            if (d == curd) run += v;
            else { atomAddF(&mh[(size_t)curd * HID + c], run); curd = d; run = v; }
        }
        atomAddF(&mh[(size_t)curd * HID + c], run);
    }
    // ---- P8: m_v segmented flush
    if (tid < 2) {
        const int c = tid;
        float run = vw_s[0] * rel_s[c];
        int curd = dst_s[0];
        for (int m = 1; m < TE; ++m) {
            int d = dst_s[m];
            float v = vw_s[m] * rel_s[2 * m + c];
            if (d == curd) run += v;
            else { atomAddF(&mv[2 * curd + c], run); curd = d; run = v; }
        }
        atomAddF(&mv[2 * curd + c], run);
    }
}

// ---------------------------------------------------------------- node kernel (MFMA)
__global__ __launch_bounds__(256, 7)
void eg_node(const float* __restrict__ x,
             const float* __restrict__ bh1, const float* __restrict__ gh1,
             const float* __restrict__ bth1, const float* __restrict__ bh2,
             const float* __restrict__ mh, const float* __restrict__ mv,
             const int* __restrict__ deg, const short* __restrict__ wt,
             float* __restrict__ out)
{
    __shared__ __align__(16) short frag_s[7 * 2 * 64 * 8];   // 14336 B
    __shared__ float psum_s[256];
    __shared__ float mu_s[32], rs_s[32];
    __shared__ float rden_s[TN], norm_s[TN];

    const int tid  = threadIdx.x;
    const int lane = tid & 63;
    const int wid  = tid >> 6;
    const int lr   = lane & 15;
    const int quad = lane >> 4;
    const int n0w  = wid * 32;
    const int n_base = blockIdx.x * TN;

    const short* Wh1T = wt + WT_WH1;
    const short* Wh2T = wt + WT_WH2;

    if (tid < TN) {
        int n = n_base + tid;
        float den = fmaxf((float)deg[n], 1.0f);
        float rd = 1.0f / den;
        float ax = mv[2 * n] * rd + 1e-8f;
        float ay = mv[2 * n + 1] * rd + 1e-8f;
        rden_s[tid] = rd;
        norm_s[tid] = sqrtf(ax * ax + ay * ay);
    }
    if (tid < 128) {
        int4 z = {0, 0, 0, 0};
        *(int4*)&frag_s[6 * 2 * 64 * 8 + tid * 8] = z;
    }
    __syncthreads();

    {
        const int e = tid & 31, slot = tid >> 5;
        const int n = n_base + e;
        {
            int c0 = slot * 8;
            const float4 a0 = *(const float4*)&x[(size_t)n * NCH + c0];
            const float4 a1 = *(const float4*)&x[(size_t)n * NCH + c0 + 4];
            uint4 pk;
            pk.x = f2bf_pk(a0.x, a0.y); pk.y = f2bf_pk(a0.z, a0.w);
            pk.z = f2bf_pk(a1.x, a1.y); pk.w = f2bf_pk(a1.z, a1.w);
            int ks = slot >> 2, kq = slot & 3;
            *(uint4*)&frag_s[fragOff(ks, e >> 4, kq * 16 + (e & 15))] = pk;
        }
        float rd = rden_s[e];
        #pragma unroll
        for (int h = 0; h < 2; ++h) {
            int o = 8 + slot + h * 8;
            int k0 = (o - 8) * 8;
            const float4 a0 = *(const float4*)&mh[(size_t)n * HID + k0];
            const float4 a1 = *(const float4*)&mh[(size_t)n * HID + k0 + 4];
            uint4 pk;
            pk.x = f2bf_pk(a0.x * rd, a0.y * rd); pk.y = f2bf_pk(a0.z * rd, a0.w * rd);
            pk.z = f2bf_pk(a1.x * rd, a1.y * rd); pk.w = f2bf_pk(a1.z * rd, a1.w * rd);
            int ks = o >> 2, kq = o & 3;
            *(uint4*)&frag_s[fragOff(ks, e >> 4, kq * 16 + (e & 15))] = pk;
        }
    }
    if (tid < TN) {
        frag_s[fragOff(6, tid >> 4, (tid & 15))] = (short)f2bf(norm_s[tid]);
    }
    __syncthreads();

    const int ncol0 = n0w + lr;
    const int ncol1 = n0w + 16 + lr;

    f32x4 zero4 = {0.f, 0.f, 0.f, 0.f};
    f32x4 acc1[2][2];
    #pragma unroll
    for (int mt = 0; mt < 2; ++mt)
        #pragma unroll
        for (int nt = 0; nt < 2; ++nt) acc1[mt][nt] = zero4;
    {
        const short* pa = &frag_s[lane * 8];
        const short* pw0 = Wh1T + ncol0 * KN1 + quad * 8;
        const short* pw1 = Wh1T + ncol1 * KN1 + quad * 8;
        #pragma unroll
        for (int ks = 0; ks < 7; ++ks) {
            bf16x8 af0 = *(const bf16x8*)&pa[ks * 1024];
            bf16x8 af1 = *(const bf16x8*)&pa[ks * 1024 + 512];
            bf16x8 bw0 = *(const bf16x8*)&pw0[ks * 32];
            bf16x8 bw1 = *(const bf16x8*)&pw1[ks * 32];
            acc1[0][0] = __builtin_amdgcn_mfma_f32_16x16x32_bf16(af0, bw0, acc1[0][0], 0, 0, 0);
            acc1[1][0] = __builtin_amdgcn_mfma_f32_16x16x32_bf16(af1, bw0, acc1[1][0], 0, 0, 0);
            acc1[0][1] = __builtin_amdgcn_mfma_f32_16x16x32_bf16(af0, bw1, acc1[0][1], 0, 0, 0);
            acc1[1][1] = __builtin_amdgcn_mfma_f32_16x16x32_bf16(af1, bw1, acc1[1][1], 0, 0, 0);
        }
    }
    {
        float b0 = bh1[ncol0], b1 = bh1[ncol1];
        #pragma unroll
        for (int mt = 0; mt < 2; ++mt)
            #pragma unroll
            for (int r = 0; r < 4; ++r) { acc1[mt][0][r] += b0; acc1[mt][1][r] += b1; }
    }

    #pragma unroll
    for (int mt = 0; mt < 2; ++mt)
        #pragma unroll
        for (int r = 0; r < 4; ++r) {
            float s = acc1[mt][0][r] + acc1[mt][1][r];
            float q = acc1[mt][0][r] * acc1[mt][0][r] + acc1[mt][1][r] * acc1[mt][1][r];
            RED16(s); RED16(q);
            if (lr == 0) {
                int row = mt * 16 + quad * 4 + r;
                psum_s[row * 4 + wid]       = s;
                psum_s[128 + row * 4 + wid] = q;
            }
        }
    __syncthreads();
    if (tid < 32) {
        float s = 0.f, q = 0.f;
        #pragma unroll
        for (int w = 0; w < 4; ++w) {
            s += psum_s[tid * 4 + w];
            q += psum_s[128 + tid * 4 + w];
        }
        float mu = s * (1.0f / HID);
        float var = q * (1.0f / HID) - mu * mu;
        mu_s[tid] = mu;
        rs_s[tid] = rsqrtf(var + LN_EPS);
    }
    __syncthreads();

    {
        float g0 = gh1[ncol0], g1 = gh1[ncol1];
        float t0 = bth1[ncol0], t1 = bth1[ncol1];
        int ks0 = ncol0 >> 5, kq0 = (ncol0 & 31) >> 3, j0 = ncol0 & 7;
        int ks1 = ncol1 >> 5, kq1 = (ncol1 & 31) >> 3, j1 = ncol1 & 7;
        short* bp0 = &frag_s[(ks0 * 128 + kq0 * 16 + quad * 4) * 8 + j0];
        short* bp1 = &frag_s[(ks1 * 128 + kq1 * 16 + quad * 4) * 8 + j1];
        #pragma unroll
        for (int mt = 0; mt < 2; ++mt)
            #pragma unroll
            for (int r = 0; r < 4; ++r) {
                int row = mt * 16 + quad * 4 + r;
                float mu = mu_s[row], rsv = rs_s[row];
                float h0 = sp((acc1[mt][0][r] - mu) * rsv * g0 + t0);
                float h1 = sp((acc1[mt][1][r] - mu) * rsv * g1 + t1);
                unsigned int ph = f2bf_pk(h0, h1);
                bp0[mt * 512 + r * 8] = (short)(ph & 0xFFFFu);
                bp1[mt * 512 + r * 8] = (short)(ph >> 16);
            }
    }
    __syncthreads();

    {
        const int col = wid * 16 + lr;
        f32x4 acc2[2] = { zero4, zero4 };
        const short* pa = &frag_s[lane * 8];
        const short* pw = Wh2T + col * KP2 + quad * 8;
        #pragma unroll
        for (int ks = 0; ks < 4; ++ks) {
            bf16x8 af0 = *(const bf16x8*)&pa[ks * 1024];
            bf16x8 af1 = *(const bf16x8*)&pa[ks * 1024 + 512];
            bf16x8 bw = *(const bf16x8*)&pw[ks * 32];
            acc2[0] = __builtin_amdgcn_mfma_f32_16x16x32_bf16(af0, bw, acc2[0], 0, 0, 0);
            acc2[1] = __builtin_amdgcn_mfma_f32_16x16x32_bf16(af1, bw, acc2[1], 0, 0, 0);
        }
        float bo = bh2[col];
        #pragma unroll
        for (int mt = 0; mt < 2; ++mt)
            #pragma unroll
            for (int r = 0; r < 4; ++r) {
                int m = mt * 16 + quad * 4 + r;
                size_t idx = (size_t)(n_base + m) * OUTC + col;
                out[idx] = x[(size_t)(n_base + m) * NCH + col] + acc2[mt][r] + bo;
            }
    }
}

// ---------------------------------------------------------------- launch
extern "C" void kernel_launch(void* const* d_in, const int* in_sizes, int n_in,
                              void* d_out, int out_size, void* d_ws, size_t ws_size,
                              hipStream_t stream)
{
    const float* x    = (const float*)d_in[0];
    const float* pos  = (const float*)d_in[1];
    const float* vel  = (const float*)d_in[2];
    const float* We1  = (const float*)d_in[3];
    const float* be1  = (const float*)d_in[4];
    const float* ge1  = (const float*)d_in[5];
    const float* bte1 = (const float*)d_in[6];
    const float* We2  = (const float*)d_in[7];
    const float* be2  = (const float*)d_in[8];
    const float* We3  = (const float*)d_in[9];
    const float* be3  = (const float*)d_in[10];
    const float* Wv1  = (const float*)d_in[11];
    const float* bv1  = (const float*)d_in[12];
    const float* gv1  = (const float*)d_in[13];
    const float* btv1 = (const float*)d_in[14];
    const float* Wv2  = (const float*)d_in[15];
    const float* bv2  = (const float*)d_in[16];
    const float* Wh1  = (const float*)d_in[17];
    const float* bh1  = (const float*)d_in[18];
    const float* gh1  = (const float*)d_in[19];
    const float* bth1 = (const float*)d_in[20];
    const float* Wh2  = (const float*)d_in[21];
    const float* bh2  = (const float*)d_in[22];
    const int*   ei   = (const int*)d_in[23];

    // workspace layout
    float* mh   = (float*)d_ws;                      // 2,560,000 f
    float* mv   = mh + (size_t)NNODE * HID;          // 40,000 f
    int*   deg  = (int*)(mv + NNODE * 2);            // 20,000 i
    int*   cur  = deg + NNODE;                       // 20,000 i
    int*   perm = cur + NNODE;                       // 640,000 i
    float* pkp  = (float*)(perm + NEDGE);            // 1,280 f
    short* wt   = (short*)(pkp + 1280);              // 110,592 s

    // zero mh, mv, deg (contiguous)
    size_t zbytes = ((size_t)NNODE * HID + NNODE * 2 + NNODE) * sizeof(float);
    hipMemsetAsync(d_ws, 0, zbytes, stream);

    eg_prep<<<dim3(NEDGE / 256), dim3(256), 0, stream>>>(
        We1, Wv1, We2, We3, Wh1, Wh2,
        be1, bv1, ge1, bte1, gv1, btv1, Wv2, be2, be3, bv2,
        ei, wt, pkp, deg);
    eg_scan<<<dim3(1), dim3(1024), 0, stream>>>(deg, cur);
    eg_scatter<<<dim3(NEDGE / 256), dim3(256), 0, stream>>>(ei, cur, perm);

    eg_edge<<<dim3(NEBLK), dim3(256), 0, stream>>>(
        x, pos, vel, pkp, wt, ei, perm, mh, mv);

    eg_node<<<dim3(NNODE / TN), dim3(256), 0, stream>>>(
        x, bh1, gh1, bth1, bh2, mh, mv, deg, wt, (float*)d_out);
}